// Round 1
// baseline (4021.005 us; speedup 1.0000x reference)
//
#include <hip/hip_runtime.h>

#define BB 4
#define HH 8
#define NSEQ 4096
#define DD 64
#define MM 266
#define CCH 128
#define NCH 32
#define NBH (BB*HH)
#define NROWS (NBH*NSEQ)

#define NORMALIZER 0.35355339059327373f
#define DIAGF 0.0625f
#define RATIO 0.0613140017f
#define KEPS 1e-4f

typedef unsigned short ushort_t;
typedef unsigned int uint_t;

__device__ __forceinline__ ushort_t f2bf(float x){
  union { float f; uint_t u; } v; v.f = x;
  uint_t r = (v.u + 0x7FFFu + ((v.u >> 16) & 1u)) >> 16;
  return (ushort_t)r;
}
__device__ __forceinline__ float bf2f(ushort_t h){
  union { uint_t u; float f; } v; v.u = ((uint_t)h) << 16;
  return v.f;
}
__device__ __forceinline__ void unpack2(uint_t w, float& lo, float& hi){
  union { uint_t u; float f; } a, b;
  a.u = w << 16; b.u = w & 0xFFFF0000u;
  lo = a.f; hi = b.f;
}

__device__ __forceinline__ float dot64(const float* sq, const float* __restrict__ pr){
  const float4* p4 = (const float4*)pr;
  float acc = 0.f;
  #pragma unroll
  for (int i=0;i<16;++i){
    float4 p = p4[i];
    acc += sq[4*i+0]*p.x + sq[4*i+1]*p.y + sq[4*i+2]*p.z + sq[4*i+3]*p.w;
  }
  return acc;
}

// ---------------- projection kernels ----------------

__global__ __launch_bounds__(256) void k_qproj(const float* __restrict__ q,
                                               const float* __restrict__ proj,
                                               ushort_t* __restrict__ qp){
  int row = blockIdx.x; int t = threadIdx.x;
  __shared__ float s_q[64];
  __shared__ float s_diag[1];
  __shared__ float s_max[4];
  const float* qr = q + (size_t)row*DD;
  if (t < 64){
    float x = qr[t]; s_q[t] = x;
    float ss = x*x;
    #pragma unroll
    for (int off=32; off>0; off>>=1) ss += __shfl_xor(ss, off);
    if (t==0) s_diag[0] = ss;
  }
  __syncthreads();
  float diag = s_diag[0]*DIAGF;
  float d1 = dot64(s_q, proj + (size_t)t*DD) * NORMALIZER;
  bool v2 = (t < MM-256);
  float d2 = 0.f;
  if (v2) d2 = dot64(s_q, proj + (size_t)(256+t)*DD) * NORMALIZER;
  float lmax = v2 ? fmaxf(d1,d2) : d1;
  #pragma unroll
  for (int off=32; off>0; off>>=1) lmax = fmaxf(lmax, __shfl_xor(lmax, off));
  if ((t&63)==0) s_max[t>>6] = lmax;
  __syncthreads();
  float rmax = fmaxf(fmaxf(s_max[0],s_max[1]), fmaxf(s_max[2],s_max[3]));
  ushort_t* o = qp + (size_t)row*MM;
  o[t] = f2bf(RATIO*(__expf(d1 - diag - rmax) + KEPS));
  if (v2) o[256+t] = f2bf(RATIO*(__expf(d2 - diag - rmax) + KEPS));
}

__global__ __launch_bounds__(256) void k_kmax(const float* __restrict__ k,
                                              const float* __restrict__ proj,
                                              float* __restrict__ rowmax){
  int row = blockIdx.x; int t = threadIdx.x;
  __shared__ float s_q[64];
  __shared__ float s_max[4];
  const float* kr = k + (size_t)row*DD;
  if (t < 64) s_q[t] = kr[t];
  __syncthreads();
  float d1 = dot64(s_q, proj + (size_t)t*DD) * NORMALIZER;
  bool v2 = (t < MM-256);
  float d2 = 0.f;
  if (v2) d2 = dot64(s_q, proj + (size_t)(256+t)*DD) * NORMALIZER;
  float lmax = v2 ? fmaxf(d1,d2) : d1;
  #pragma unroll
  for (int off=32; off>0; off>>=1) lmax = fmaxf(lmax, __shfl_xor(lmax, off));
  if ((t&63)==0) s_max[t>>6] = lmax;
  __syncthreads();
  if (t==0) rowmax[row] = fmaxf(fmaxf(s_max[0],s_max[1]), fmaxf(s_max[2],s_max[3]));
}

__global__ __launch_bounds__(256) void k_gmax(const float* __restrict__ rowmax,
                                              float* __restrict__ gmax){
  __shared__ float s[4];
  int t = threadIdx.x;
  float m = -1e30f;
  for (int i=t;i<NROWS;i+=256) m = fmaxf(m, rowmax[i]);
  #pragma unroll
  for (int off=32; off>0; off>>=1) m = fmaxf(m, __shfl_xor(m, off));
  if ((t&63)==0) s[t>>6] = m;
  __syncthreads();
  if (t==0) gmax[0] = fmaxf(fmaxf(s[0],s[1]), fmaxf(s[2],s[3]));
}

__global__ __launch_bounds__(256) void k_kproj(const float* __restrict__ k,
                                               const float* __restrict__ proj,
                                               const float* __restrict__ gmax,
                                               ushort_t* __restrict__ kp){
  int row = blockIdx.x; int t = threadIdx.x;
  __shared__ float s_q[64];
  __shared__ float s_diag[1];
  const float* kr = k + (size_t)row*DD;
  if (t < 64){
    float x = kr[t]; s_q[t] = x;
    float ss = x*x;
    #pragma unroll
    for (int off=32; off>0; off>>=1) ss += __shfl_xor(ss, off);
    if (t==0) s_diag[0] = ss;
  }
  __syncthreads();
  float diag = s_diag[0]*DIAGF;
  float stab = gmax[0];
  float d1 = dot64(s_q, proj + (size_t)t*DD) * NORMALIZER;
  bool v2 = (t < MM-256);
  float d2 = 0.f;
  if (v2) d2 = dot64(s_q, proj + (size_t)(256+t)*DD) * NORMALIZER;
  ushort_t* o = kp + (size_t)row*MM;
  o[t] = f2bf(RATIO*(__expf(d1 - diag - stab) + KEPS));
  if (v2) o[256+t] = f2bf(RATIO*(__expf(d2 - diag - stab) + KEPS));
}

// ---------------- chunk sums: CTX_c = kp^T v, z_c = colsum(kp) ----------------

__global__ __launch_bounds__(256) void k_chunksum(const ushort_t* __restrict__ kp,
                                                  const float* __restrict__ v,
                                                  float* __restrict__ ctx,
                                                  float* __restrict__ z){
  __shared__ float v_s[CCH][DD];       // 32 KB
  __shared__ ushort_t kp_s[32][272];   // 17 KB (zero-padded cols 266..271)
  const int blk = blockIdx.x, bh = blk>>5, ch = blk&31;
  const int t = threadIdx.x, e = t&63, g = t>>6;
  const int row0 = ch*CCH;
  const float* vg = v + (size_t)bh*NSEQ*DD + (size_t)row0*DD;
  for (int idx=t; idx<CCH*DD; idx+=256) v_s[idx>>6][idx&63] = vg[idx];
  float acc[17][4];
  #pragma unroll
  for (int j=0;j<17;++j){ acc[j][0]=0.f; acc[j][1]=0.f; acc[j][2]=0.f; acc[j][3]=0.f; }
  float zac1 = 0.f, zac2 = 0.f;
  const bool has2 = (256 + t) < MM;
  const ushort_t* kg = kp + (size_t)bh*NSEQ*MM + (size_t)row0*MM;
  for (int is=0; is<4; ++is){
    __syncthreads();
    for (int idx=t; idx<32*272; idx+=256){
      int r = idx/272, c2 = idx - r*272;
      kp_s[r][c2] = (c2<MM) ? kg[(size_t)(is*32+r)*MM + c2] : (ushort_t)0;
    }
    __syncthreads();
    for (int il=0; il<32; ++il){
      float vv = v_s[is*32+il][e];
      #pragma unroll
      for (int j=0;j<17;++j){
        uint2 w = *(const uint2*)(&kp_s[il][16*j + 4*g]);
        float f0,f1,f2,f3;
        unpack2(w.x, f0, f1); unpack2(w.y, f2, f3);
        acc[j][0] += f0*vv; acc[j][1] += f1*vv; acc[j][2] += f2*vv; acc[j][3] += f3*vv;
      }
    }
    // z partials (sum of kp over the 32 staged rows)
    {
      float s1 = 0.f, s2 = 0.f;
      for (int r=0;r<32;++r){
        s1 += bf2f(kp_s[r][t]);
        if (has2) s2 += bf2f(kp_s[r][256+t]);
      }
      zac1 += s1; if (has2) zac2 += s2;
    }
  }
  float* cg = ctx + (size_t)blk*MM*DD;
  #pragma unroll
  for (int j=0;j<17;++j){
    #pragma unroll
    for (int p=0;p<4;++p){
      int m = 16*j + 4*g + p;
      if (m < MM) cg[(size_t)m*DD + e] = acc[j][p];
    }
  }
  float* zgo = z + (size_t)blk*MM;
  zgo[t] = zac1;
  if (has2) zgo[256+t] = zac2;
}

// ---------------- exclusive prefix over chunks ----------------

__global__ __launch_bounds__(256) void k_prefix_ctx(float* __restrict__ ctx){
  int blk = blockIdx.x; int bh = blk/67, mg = blk%67;
  int t = threadIdx.x; int mo = t>>6, e = t&63;
  int m = mg*4 + mo;
  if (m >= MM) return;
  size_t base = (size_t)bh*NCH*MM*DD + (size_t)m*DD + e;
  float run = 0.f;
  for (int c=0;c<NCH;++c){
    size_t idx = base + (size_t)c*MM*DD;
    float cur = ctx[idx]; ctx[idx] = run; run += cur;
  }
}

__global__ __launch_bounds__(256) void k_prefix_z(float* __restrict__ z){
  int bh = blockIdx.x, t = threadIdx.x;
  size_t base = (size_t)bh*NCH*MM;
  float run1 = 0.f, run2 = 0.f;
  bool has2 = (256+t) < MM;
  for (int c=0;c<NCH;++c){
    size_t o = base + (size_t)c*MM;
    float c1 = z[o+t]; z[o+t] = run1; run1 += c1;
    if (has2){ float c2 = z[o+256+t]; z[o+256+t] = run2; run2 += c2; }
  }
}

// ---------------- per-chunk output ----------------
// out = masked(qp kp^T) v + qp CTXp ; D = rowsum(masked A) + qp zp ; out /= D

__global__ __launch_bounds__(256) void k_output(const ushort_t* __restrict__ qp,
                                                const ushort_t* __restrict__ kp,
                                                const float* __restrict__ v,
                                                const float* __restrict__ ctx,
                                                const float* __restrict__ z,
                                                float* __restrict__ out){
  __shared__ __align__(16) char lds[34816 + 16384 + 512 + 256];
  ushort_t* qp_t = (ushort_t*)lds;                       // [64][136] bf16
  ushort_t* kp_t = (ushort_t*)(lds + 17408);             // [64][136] bf16
  ushort_t* A_sT = (ushort_t*)lds;                       // [128 c][136 r] bf16 (aliases qp_t+kp_t)
  float*    ctx_s = (float*)(lds + 17408);               // [64][68] f32 (aliases kp_t)
  ushort_t* v_s  = (ushort_t*)(lds + 34816);             // [128][64] bf16
  float*    Drow = (float*)(lds + 34816 + 16384);        // [128]
  float*    zp_s = (float*)(lds + 34816 + 16384 + 512);  // [64]

  const int blk = blockIdx.x;
  const int bh = blk >> 5, ch = blk & 31;
  const int t = threadIdx.x;
  const int tx = t & 15, ty = t >> 4;
  const int r0 = ty*8, c0 = tx*8, e0 = tx*4;
  const int row0 = ch*CCH;

  const ushort_t* qg = qp + (size_t)bh*NSEQ*MM + (size_t)row0*MM;
  const ushort_t* kg = kp + (size_t)bh*NSEQ*MM + (size_t)row0*MM;

  { const float* vg = v + (size_t)bh*NSEQ*DD + (size_t)row0*DD;
    for (int idx=t; idx<CCH*DD; idx+=256) v_s[idx] = f2bf(vg[idx]); }

  float Aacc[8][8];
  #pragma unroll
  for (int u=0;u<8;++u){
    #pragma unroll
    for (int w=0;w<8;++w) Aacc[u][w]=0.f;
  }

  // ---- phase A: A = qp_c kp_c^T over K=266 (tiles of 64, zero-padded) ----
  for (int mt=0; mt<5; ++mt){
    const int m0 = mt*64;
    const int mlim = (mt==4) ? (MM-256) : 64;
    for (int idx=t; idx<8192; idx+=256){
      int i = idx>>6, j = idx&63;
      ushort_t qv = 0, kv = 0;
      if (j < mlim){ qv = qg[(size_t)i*MM + m0 + j]; kv = kg[(size_t)i*MM + m0 + j]; }
      qp_t[j*136 + i] = qv;
      kp_t[j*136 + i] = kv;
    }
    __syncthreads();
    for (int kk=0; kk<64; ++kk){
      uint4 qa = *(const uint4*)(qp_t + kk*136 + r0);
      uint4 kb = *(const uint4*)(kp_t + kk*136 + c0);
      float a[8], b[8];
      unpack2(qa.x,a[0],a[1]); unpack2(qa.y,a[2],a[3]); unpack2(qa.z,a[4],a[5]); unpack2(qa.w,a[6],a[7]);
      unpack2(kb.x,b[0],b[1]); unpack2(kb.y,b[2],b[3]); unpack2(kb.z,b[4],b[5]); unpack2(kb.w,b[6],b[7]);
      #pragma unroll
      for (int u=0;u<8;++u){
        #pragma unroll
        for (int w=0;w<8;++w) Aacc[u][w] += a[u]*b[w];
      }
    }
    __syncthreads();
  }

  // ---- mask, D rowsum partial, write A^T (bf16) ----
  float Dsum[8];
  #pragma unroll
  for (int u=0;u<8;++u) Dsum[u]=0.f;
  #pragma unroll
  for (int cv=0; cv<8; ++cv){
    int c = c0 + cv;
    float tmp[8];
    #pragma unroll
    for (int u=0;u<8;++u){ float val = (c <= r0+u) ? Aacc[u][cv] : 0.f; tmp[u]=val; Dsum[u]+=val; }
    uint4 w;
    w.x = (uint_t)f2bf(tmp[0]) | ((uint_t)f2bf(tmp[1])<<16);
    w.y = (uint_t)f2bf(tmp[2]) | ((uint_t)f2bf(tmp[3])<<16);
    w.z = (uint_t)f2bf(tmp[4]) | ((uint_t)f2bf(tmp[5])<<16);
    w.w = (uint_t)f2bf(tmp[6]) | ((uint_t)f2bf(tmp[7])<<16);
    *(uint4*)(A_sT + c*136 + r0) = w;
  }
  #pragma unroll
  for (int u=0;u<8;++u){
    float d = Dsum[u];
    d += __shfl_xor(d,1); d += __shfl_xor(d,2); d += __shfl_xor(d,4); d += __shfl_xor(d,8);
    if (tx==0) Drow[r0+u] = d;
  }
  __syncthreads();

  // ---- part 1: out = masked(A) @ v ----
  float oacc[8][4];
  #pragma unroll
  for (int u=0;u<8;++u){ oacc[u][0]=0.f; oacc[u][1]=0.f; oacc[u][2]=0.f; oacc[u][3]=0.f; }
  for (int c=0;c<CCH;++c){
    uint4 aw = *(const uint4*)(A_sT + c*136 + r0);
    float a[8];
    unpack2(aw.x,a[0],a[1]); unpack2(aw.y,a[2],a[3]); unpack2(aw.z,a[4],a[5]); unpack2(aw.w,a[6],a[7]);
    uint2 vw = *(const uint2*)(v_s + c*64 + e0);
    float vv[4]; unpack2(vw.x, vv[0], vv[1]); unpack2(vw.y, vv[2], vv[3]);
    #pragma unroll
    for (int u=0;u<8;++u){
      oacc[u][0] += a[u]*vv[0]; oacc[u][1] += a[u]*vv[1];
      oacc[u][2] += a[u]*vv[2]; oacc[u][3] += a[u]*vv[3];
    }
  }
  __syncthreads();

  // ---- part 2: out += qp @ CTXp ; D += qp . zp ----
  const float* ctxg = ctx + (size_t)blk*MM*DD;
  const float* zg = z + (size_t)blk*MM;
  float Dz = 0.f;
  const int rD = t>>1, hD = t&1;
  for (int mt=0; mt<5; ++mt){
    const int m0 = mt*64;
    const int mlim = (mt==4) ? (MM-256) : 64;
    for (int idx=t; idx<8192; idx+=256){
      int i = idx>>6, j = idx&63;
      qp_t[j*136+i] = (j<mlim) ? qg[(size_t)i*MM + m0 + j] : (ushort_t)0;
    }
    for (int idx=t; idx<4096; idx+=256){
      int kk = idx>>6, ee = idx&63;
      ctx_s[kk*68+ee] = (kk<mlim) ? ctxg[(size_t)(m0+kk)*DD + ee] : 0.f;
    }
    if (t<64) zp_s[t] = (t<mlim) ? zg[m0+t] : 0.f;
    __syncthreads();
    for (int kk=0;kk<64;++kk){
      uint4 qa = *(const uint4*)(qp_t + kk*136 + r0);
      float a[8];
      unpack2(qa.x,a[0],a[1]); unpack2(qa.y,a[2],a[3]); unpack2(qa.z,a[4],a[5]); unpack2(qa.w,a[6],a[7]);
      float4 cv = *(const float4*)(ctx_s + kk*68 + e0);
      #pragma unroll
      for (int u=0;u<8;++u){
        oacc[u][0] += a[u]*cv.x; oacc[u][1] += a[u]*cv.y;
        oacc[u][2] += a[u]*cv.z; oacc[u][3] += a[u]*cv.w;
      }
    }
    for (int kk=hD*32; kk<hD*32+32; ++kk)
      Dz += bf2f(qp_t[kk*136 + rD]) * zp_s[kk];
    __syncthreads();
  }
  Dz += __shfl_xor(Dz, 1);
  if (hD==0) Drow[rD] += Dz;
  __syncthreads();

  float* og = out + (size_t)bh*NSEQ*DD + (size_t)row0*DD;
  #pragma unroll
  for (int u=0;u<8;++u){
    float dinv = 1.0f / Drow[r0+u];
    float4 o;
    o.x = oacc[u][0]*dinv; o.y = oacc[u][1]*dinv;
    o.z = oacc[u][2]*dinv; o.w = oacc[u][3]*dinv;
    *(float4*)(og + (size_t)(r0+u)*DD + e0) = o;
  }
}

// ---------------- launch ----------------

extern "C" void kernel_launch(void* const* d_in, const int* in_sizes, int n_in,
                              void* d_out, int out_size, void* d_ws, size_t ws_size,
                              hipStream_t stream) {
  const float* q    = (const float*)d_in[0];
  const float* k    = (const float*)d_in[1];
  const float* v    = (const float*)d_in[2];
  const float* proj = (const float*)d_in[3];
  float* out = (float*)d_out;
  char* ws = (char*)d_ws;

  // ws layout (bytes)
  const size_t QP_OFF   = 0;                    // bf16 [NBH][N][M]  = 69,730,304
  const size_t KP_OFF   = 69730304ull;          // bf16 [NBH][N][M]  = 69,730,304
  const size_t CTX_OFF  = 139460608ull;         // f32  [NBH][NC][M][D] = 69,730,304
  const size_t Z_OFF    = 209190912ull;         // f32  [NBH][NC][M] = 1,089,536
  const size_t RMAX_OFF = 210280448ull;         // f32  [NROWS] = 524,288
  const size_t GMAX_OFF = 210804736ull;         // f32  [1]
  if (ws_size < 210805000ull) return;           // insufficient scratch -> fail loudly

  ushort_t* qp   = (ushort_t*)(ws + QP_OFF);
  ushort_t* kp   = (ushort_t*)(ws + KP_OFF);
  float* ctx     = (float*)(ws + CTX_OFF);
  float* z       = (float*)(ws + Z_OFF);
  float* rowmax  = (float*)(ws + RMAX_OFF);
  float* gmax    = (float*)(ws + GMAX_OFF);

  k_qproj   <<<NROWS, 256, 0, stream>>>(q, proj, qp);
  k_kmax    <<<NROWS, 256, 0, stream>>>(k, proj, rowmax);
  k_gmax    <<<1, 256, 0, stream>>>(rowmax, gmax);
  k_kproj   <<<NROWS, 256, 0, stream>>>(k, proj, gmax, kp);
  k_chunksum<<<NBH*NCH, 256, 0, stream>>>(kp, v, ctx, z);
  k_prefix_ctx<<<NBH*67, 256, 0, stream>>>(ctx);
  k_prefix_z<<<NBH, 256, 0, stream>>>(z);
  k_output  <<<NBH*NCH, 256, 0, stream>>>(qp, kp, v, ctx, z, out);
}

// Round 2
// 1306.003 us; speedup vs baseline: 3.0789x; 3.0789x over previous
//
#include <hip/hip_runtime.h>

#define BB 4
#define HH 8
#define NSEQ 4096
#define DD 64
#define MM 266
#define CCH 128
#define NCH 32
#define NBH (BB*HH)
#define NROWS (NBH*NSEQ)

#define NORMALIZER 0.35355339059327373f
#define DIAGF 0.0625f
#define RATIO 0.0613140017f
#define KEPS 1e-4f

typedef unsigned short ushort_t;
typedef unsigned int uint_t;

__device__ __forceinline__ ushort_t f2bf(float x){
  union { float f; uint_t u; } v; v.f = x;
  uint_t r = (v.u + 0x7FFFu + ((v.u >> 16) & 1u)) >> 16;
  return (ushort_t)r;
}
__device__ __forceinline__ float bf2f(ushort_t h){
  union { uint_t u; float f; } v; v.u = ((uint_t)h) << 16;
  return v.f;
}
__device__ __forceinline__ void unpack2(uint_t w, float& lo, float& hi){
  union { uint_t u; float f; } a, b;
  a.u = w << 16; b.u = w & 0xFFFF0000u;
  lo = a.f; hi = b.f;
}

// dot of a 64-float row (in registers, as 16 float4) with an LDS-resident
// projection row (broadcast reads, conflict-free)
__device__ __forceinline__ float dot16(const float4* r, const float4* p){
  float acc = 0.f;
  #pragma unroll
  for (int i=0;i<16;++i){
    float4 a = r[i], b = p[i];
    acc += a.x*b.x + a.y*b.y + a.z*b.z + a.w*b.w;
  }
  return acc;
}

// ---------------- projection kernels (256 rows/block, row/thread) ----------------

__global__ __launch_bounds__(256) void k_qproj2(const float* __restrict__ q,
                                                const float* __restrict__ proj,
                                                ushort_t* __restrict__ qp){
  __shared__ float4 pj[MM*16];  // 68 KB, whole projection matrix
  const int t = threadIdx.x;
  const float4* pg = (const float4*)proj;
  for (int i=t; i<MM*16; i+=256) pj[i] = pg[i];
  __syncthreads();

  const size_t row = (size_t)blockIdx.x*256 + t;
  const float4* qg = (const float4*)(q + row*DD);
  float4 r[16];
  float ss = 0.f;
  #pragma unroll
  for (int i=0;i<16;++i){
    float4 a = qg[i];
    ss += a.x*a.x + a.y*a.y + a.z*a.z + a.w*a.w;
    a.x *= NORMALIZER; a.y *= NORMALIZER; a.z *= NORMALIZER; a.w *= NORMALIZER;
    r[i] = a;
  }
  const float diag = ss * DIAGF;

  // pass 1: row max of data_dash
  float mx = -1e30f;
  for (int m=0;m<MM;m+=2){
    float d0 = dot16(r, pj + (size_t)m*16);
    float d1 = dot16(r, pj + (size_t)(m+1)*16);
    mx = fmaxf(mx, fmaxf(d0,d1));
  }

  // pass 2: recompute, exp, pack 2 bf16 per uint store
  uint_t* o = (uint_t*)(qp + row*MM);
  const float sub = diag + mx;
  for (int m=0;m<MM;m+=2){
    float d0 = dot16(r, pj + (size_t)m*16);
    float d1 = dot16(r, pj + (size_t)(m+1)*16);
    float v0 = RATIO*(__expf(d0 - sub) + KEPS);
    float v1 = RATIO*(__expf(d1 - sub) + KEPS);
    o[m>>1] = (uint_t)f2bf(v0) | ((uint_t)f2bf(v1) << 16);
  }
}

__global__ __launch_bounds__(256) void k_kmax2(const float* __restrict__ k,
                                               const float* __restrict__ proj,
                                               float* __restrict__ rowmax){
  __shared__ float4 pj[MM*16];
  const int t = threadIdx.x;
  const float4* pg = (const float4*)proj;
  for (int i=t; i<MM*16; i+=256) pj[i] = pg[i];
  __syncthreads();

  const size_t row = (size_t)blockIdx.x*256 + t;
  const float4* kg = (const float4*)(k + row*DD);
  float4 r[16];
  #pragma unroll
  for (int i=0;i<16;++i){
    float4 a = kg[i];
    a.x *= NORMALIZER; a.y *= NORMALIZER; a.z *= NORMALIZER; a.w *= NORMALIZER;
    r[i] = a;
  }
  float mx = -1e30f;
  for (int m=0;m<MM;m+=2){
    float d0 = dot16(r, pj + (size_t)m*16);
    float d1 = dot16(r, pj + (size_t)(m+1)*16);
    mx = fmaxf(mx, fmaxf(d0,d1));
  }
  rowmax[row] = mx;
}

__global__ __launch_bounds__(256) void k_gmax(const float* __restrict__ rowmax,
                                              float* __restrict__ gmax){
  __shared__ float s[4];
  int t = threadIdx.x;
  float m = -1e30f;
  for (int i=t;i<NROWS;i+=256) m = fmaxf(m, rowmax[i]);
  #pragma unroll
  for (int off=32; off>0; off>>=1) m = fmaxf(m, __shfl_xor(m, off));
  if ((t&63)==0) s[t>>6] = m;
  __syncthreads();
  if (t==0) gmax[0] = fmaxf(fmaxf(s[0],s[1]), fmaxf(s[2],s[3]));
}

__global__ __launch_bounds__(256) void k_kproj2(const float* __restrict__ k,
                                                const float* __restrict__ proj,
                                                const float* __restrict__ gmax,
                                                ushort_t* __restrict__ kp){
  __shared__ float4 pj[MM*16];
  const int t = threadIdx.x;
  const float4* pg = (const float4*)proj;
  for (int i=t; i<MM*16; i+=256) pj[i] = pg[i];
  __syncthreads();

  const size_t row = (size_t)blockIdx.x*256 + t;
  const float4* kg = (const float4*)(k + row*DD);
  float4 r[16];
  float ss = 0.f;
  #pragma unroll
  for (int i=0;i<16;++i){
    float4 a = kg[i];
    ss += a.x*a.x + a.y*a.y + a.z*a.z + a.w*a.w;
    a.x *= NORMALIZER; a.y *= NORMALIZER; a.z *= NORMALIZER; a.w *= NORMALIZER;
    r[i] = a;
  }
  const float sub = ss * DIAGF + gmax[0];

  uint_t* o = (uint_t*)(kp + row*MM);
  for (int m=0;m<MM;m+=2){
    float d0 = dot16(r, pj + (size_t)m*16);
    float d1 = dot16(r, pj + (size_t)(m+1)*16);
    float v0 = RATIO*(__expf(d0 - sub) + KEPS);
    float v1 = RATIO*(__expf(d1 - sub) + KEPS);
    o[m>>1] = (uint_t)f2bf(v0) | ((uint_t)f2bf(v1) << 16);
  }
}

// ---------------- chunk sums: CTX_c = kp^T v, z_c = colsum(kp) ----------------

__global__ __launch_bounds__(256) void k_chunksum(const ushort_t* __restrict__ kp,
                                                  const float* __restrict__ v,
                                                  float* __restrict__ ctx,
                                                  float* __restrict__ z){
  __shared__ float v_s[CCH][DD];       // 32 KB
  __shared__ ushort_t kp_s[32][272];   // 17 KB (zero-padded cols 266..271)
  const int blk = blockIdx.x, bh = blk>>5, ch = blk&31;
  const int t = threadIdx.x, e = t&63, g = t>>6;
  const int row0 = ch*CCH;
  const float* vg = v + (size_t)bh*NSEQ*DD + (size_t)row0*DD;
  for (int idx=t; idx<CCH*DD; idx+=256) v_s[idx>>6][idx&63] = vg[idx];
  float acc[17][4];
  #pragma unroll
  for (int j=0;j<17;++j){ acc[j][0]=0.f; acc[j][1]=0.f; acc[j][2]=0.f; acc[j][3]=0.f; }
  float zac1 = 0.f, zac2 = 0.f;
  const bool has2 = (256 + t) < MM;
  const ushort_t* kg = kp + (size_t)bh*NSEQ*MM + (size_t)row0*MM;
  for (int is=0; is<4; ++is){
    __syncthreads();
    for (int idx=t; idx<32*272; idx+=256){
      int r = idx/272, c2 = idx - r*272;
      kp_s[r][c2] = (c2<MM) ? kg[(size_t)(is*32+r)*MM + c2] : (ushort_t)0;
    }
    __syncthreads();
    for (int il=0; il<32; ++il){
      float vv = v_s[is*32+il][e];
      #pragma unroll
      for (int j=0;j<17;++j){
        uint2 w = *(const uint2*)(&kp_s[il][16*j + 4*g]);
        float f0,f1,f2,f3;
        unpack2(w.x, f0, f1); unpack2(w.y, f2, f3);
        acc[j][0] += f0*vv; acc[j][1] += f1*vv; acc[j][2] += f2*vv; acc[j][3] += f3*vv;
      }
    }
    {
      float s1 = 0.f, s2 = 0.f;
      for (int r=0;r<32;++r){
        s1 += bf2f(kp_s[r][t]);
        if (has2) s2 += bf2f(kp_s[r][256+t]);
      }
      zac1 += s1; if (has2) zac2 += s2;
    }
  }
  float* cg = ctx + (size_t)blk*MM*DD;
  #pragma unroll
  for (int j=0;j<17;++j){
    #pragma unroll
    for (int p=0;p<4;++p){
      int m = 16*j + 4*g + p;
      if (m < MM) cg[(size_t)m*DD + e] = acc[j][p];
    }
  }
  float* zgo = z + (size_t)blk*MM;
  zgo[t] = zac1;
  if (has2) zgo[256+t] = zac2;
}

// ---------------- exclusive prefix over chunks ----------------

__global__ __launch_bounds__(256) void k_prefix_ctx(float* __restrict__ ctx){
  int blk = blockIdx.x; int bh = blk/67, mg = blk%67;
  int t = threadIdx.x; int mo = t>>6, e = t&63;
  int m = mg*4 + mo;
  if (m >= MM) return;
  size_t base = (size_t)bh*NCH*MM*DD + (size_t)m*DD + e;
  float run = 0.f;
  for (int c=0;c<NCH;++c){
    size_t idx = base + (size_t)c*MM*DD;
    float cur = ctx[idx]; ctx[idx] = run; run += cur;
  }
}

__global__ __launch_bounds__(256) void k_prefix_z(float* __restrict__ z){
  int bh = blockIdx.x, t = threadIdx.x;
  size_t base = (size_t)bh*NCH*MM;
  float run1 = 0.f, run2 = 0.f;
  bool has2 = (256+t) < MM;
  for (int c=0;c<NCH;++c){
    size_t o = base + (size_t)c*MM;
    float c1 = z[o+t]; z[o+t] = run1; run1 += c1;
    if (has2){ float c2 = z[o+256+t]; z[o+256+t] = run2; run2 += c2; }
  }
}

// ---------------- per-chunk output ----------------
// out = masked(qp kp^T) v + qp CTXp ; D = rowsum(masked A) + qp zp ; out /= D

__global__ __launch_bounds__(256) void k_output(const ushort_t* __restrict__ qp,
                                                const ushort_t* __restrict__ kp,
                                                const float* __restrict__ v,
                                                const float* __restrict__ ctx,
                                                const float* __restrict__ z,
                                                float* __restrict__ out){
  __shared__ __align__(16) char lds[34816 + 16384 + 512 + 256];
  ushort_t* qp_t = (ushort_t*)lds;                       // [64][136] bf16
  ushort_t* kp_t = (ushort_t*)(lds + 17408);             // [64][136] bf16
  ushort_t* A_sT = (ushort_t*)lds;                       // [128 c][136 r] bf16 (aliases qp_t+kp_t)
  float*    ctx_s = (float*)(lds + 17408);               // [64][68] f32 (aliases kp_t)
  ushort_t* v_s  = (ushort_t*)(lds + 34816);             // [128][64] bf16
  float*    Drow = (float*)(lds + 34816 + 16384);        // [128]
  float*    zp_s = (float*)(lds + 34816 + 16384 + 512);  // [64]

  const int blk = blockIdx.x;
  const int bh = blk >> 5, ch = blk & 31;
  const int t = threadIdx.x;
  const int tx = t & 15, ty = t >> 4;
  const int r0 = ty*8, c0 = tx*8, e0 = tx*4;
  const int row0 = ch*CCH;

  const ushort_t* qg = qp + (size_t)bh*NSEQ*MM + (size_t)row0*MM;
  const ushort_t* kg = kp + (size_t)bh*NSEQ*MM + (size_t)row0*MM;

  { const float* vg = v + (size_t)bh*NSEQ*DD + (size_t)row0*DD;
    for (int idx=t; idx<CCH*DD; idx+=256) v_s[idx] = f2bf(vg[idx]); }

  float Aacc[8][8];
  #pragma unroll
  for (int u=0;u<8;++u){
    #pragma unroll
    for (int w=0;w<8;++w) Aacc[u][w]=0.f;
  }

  // ---- phase A: A = qp_c kp_c^T over K=266 (tiles of 64, zero-padded) ----
  for (int mt=0; mt<5; ++mt){
    const int m0 = mt*64;
    const int mlim = (mt==4) ? (MM-256) : 64;
    for (int idx=t; idx<8192; idx+=256){
      int i = idx>>6, j = idx&63;
      ushort_t qv = 0, kv = 0;
      if (j < mlim){ qv = qg[(size_t)i*MM + m0 + j]; kv = kg[(size_t)i*MM + m0 + j]; }
      qp_t[j*136 + i] = qv;
      kp_t[j*136 + i] = kv;
    }
    __syncthreads();
    for (int kk=0; kk<64; ++kk){
      uint4 qa = *(const uint4*)(qp_t + kk*136 + r0);
      uint4 kb = *(const uint4*)(kp_t + kk*136 + c0);
      float a[8], b[8];
      unpack2(qa.x,a[0],a[1]); unpack2(qa.y,a[2],a[3]); unpack2(qa.z,a[4],a[5]); unpack2(qa.w,a[6],a[7]);
      unpack2(kb.x,b[0],b[1]); unpack2(kb.y,b[2],b[3]); unpack2(kb.z,b[4],b[5]); unpack2(kb.w,b[6],b[7]);
      #pragma unroll
      for (int u=0;u<8;++u){
        #pragma unroll
        for (int w=0;w<8;++w) Aacc[u][w] += a[u]*b[w];
      }
    }
    __syncthreads();
  }

  // ---- mask, D rowsum partial, write A^T (bf16) ----
  float Dsum[8];
  #pragma unroll
  for (int u=0;u<8;++u) Dsum[u]=0.f;
  #pragma unroll
  for (int cv=0; cv<8; ++cv){
    int c = c0 + cv;
    float tmp[8];
    #pragma unroll
    for (int u=0;u<8;++u){ float val = (c <= r0+u) ? Aacc[u][cv] : 0.f; tmp[u]=val; Dsum[u]+=val; }
    uint4 w;
    w.x = (uint_t)f2bf(tmp[0]) | ((uint_t)f2bf(tmp[1])<<16);
    w.y = (uint_t)f2bf(tmp[2]) | ((uint_t)f2bf(tmp[3])<<16);
    w.z = (uint_t)f2bf(tmp[4]) | ((uint_t)f2bf(tmp[5])<<16);
    w.w = (uint_t)f2bf(tmp[6]) | ((uint_t)f2bf(tmp[7])<<16);
    *(uint4*)(A_sT + c*136 + r0) = w;
  }
  #pragma unroll
  for (int u=0;u<8;++u){
    float d = Dsum[u];
    d += __shfl_xor(d,1); d += __shfl_xor(d,2); d += __shfl_xor(d,4); d += __shfl_xor(d,8);
    if (tx==0) Drow[r0+u] = d;
  }
  __syncthreads();

  // ---- part 1: out = masked(A) @ v ----
  float oacc[8][4];
  #pragma unroll
  for (int u=0;u<8;++u){ oacc[u][0]=0.f; oacc[u][1]=0.f; oacc[u][2]=0.f; oacc[u][3]=0.f; }
  for (int c=0;c<CCH;++c){
    uint4 aw = *(const uint4*)(A_sT + c*136 + r0);
    float a[8];
    unpack2(aw.x,a[0],a[1]); unpack2(aw.y,a[2],a[3]); unpack2(aw.z,a[4],a[5]); unpack2(aw.w,a[6],a[7]);
    uint2 vw = *(const uint2*)(v_s + c*64 + e0);
    float vv[4]; unpack2(vw.x, vv[0], vv[1]); unpack2(vw.y, vv[2], vv[3]);
    #pragma unroll
    for (int u=0;u<8;++u){
      oacc[u][0] += a[u]*vv[0]; oacc[u][1] += a[u]*vv[1];
      oacc[u][2] += a[u]*vv[2]; oacc[u][3] += a[u]*vv[3];
    }
  }
  __syncthreads();

  // ---- part 2: out += qp @ CTXp ; D += qp . zp ----
  const float* ctxg = ctx + (size_t)blk*MM*DD;
  const float* zg = z + (size_t)blk*MM;
  float Dz = 0.f;
  const int rD = t>>1, hD = t&1;
  for (int mt=0; mt<5; ++mt){
    const int m0 = mt*64;
    const int mlim = (mt==4) ? (MM-256) : 64;
    for (int idx=t; idx<8192; idx+=256){
      int i = idx>>6, j = idx&63;
      qp_t[j*136+i] = (j<mlim) ? qg[(size_t)i*MM + m0 + j] : (ushort_t)0;
    }
    for (int idx=t; idx<4096; idx+=256){
      int kk = idx>>6, ee = idx&63;
      ctx_s[kk*68+ee] = (kk<mlim) ? ctxg[(size_t)(m0+kk)*DD + ee] : 0.f;
    }
    if (t<64) zp_s[t] = (t<mlim) ? zg[m0+t] : 0.f;
    __syncthreads();
    for (int kk=0;kk<64;++kk){
      uint4 qa = *(const uint4*)(qp_t + kk*136 + r0);
      float a[8];
      unpack2(qa.x,a[0],a[1]); unpack2(qa.y,a[2],a[3]); unpack2(qa.z,a[4],a[5]); unpack2(qa.w,a[6],a[7]);
      float4 cv = *(const float4*)(ctx_s + kk*68 + e0);
      #pragma unroll
      for (int u=0;u<8;++u){
        oacc[u][0] += a[u]*cv.x; oacc[u][1] += a[u]*cv.y;
        oacc[u][2] += a[u]*cv.z; oacc[u][3] += a[u]*cv.w;
      }
    }
    for (int kk=hD*32; kk<hD*32+32; ++kk)
      Dz += bf2f(qp_t[kk*136 + rD]) * zp_s[kk];
    __syncthreads();
  }
  Dz += __shfl_xor(Dz, 1);
  if (hD==0) Drow[rD] += Dz;
  __syncthreads();

  float* og = out + (size_t)bh*NSEQ*DD + (size_t)row0*DD;
  #pragma unroll
  for (int u=0;u<8;++u){
    float dinv = 1.0f / Drow[r0+u];
    float4 o;
    o.x = oacc[u][0]*dinv; o.y = oacc[u][1]*dinv;
    o.z = oacc[u][2]*dinv; o.w = oacc[u][3]*dinv;
    *(float4*)(og + (size_t)(r0+u)*DD + e0) = o;
  }
}

// ---------------- launch ----------------

extern "C" void kernel_launch(void* const* d_in, const int* in_sizes, int n_in,
                              void* d_out, int out_size, void* d_ws, size_t ws_size,
                              hipStream_t stream) {
  const float* q    = (const float*)d_in[0];
  const float* k    = (const float*)d_in[1];
  const float* v    = (const float*)d_in[2];
  const float* proj = (const float*)d_in[3];
  float* out = (float*)d_out;
  char* ws = (char*)d_ws;

  // ws layout (bytes)
  const size_t QP_OFF   = 0;                    // bf16 [NBH][N][M]  = 69,730,304
  const size_t KP_OFF   = 69730304ull;          // bf16 [NBH][N][M]  = 69,730,304
  const size_t CTX_OFF  = 139460608ull;         // f32  [NBH][NC][M][D] = 69,730,304
  const size_t Z_OFF    = 209190912ull;         // f32  [NBH][NC][M] = 1,089,536
  const size_t RMAX_OFF = 210280448ull;         // f32  [NROWS] = 524,288
  const size_t GMAX_OFF = 210804736ull;         // f32  [1]
  if (ws_size < 210805000ull) return;

  ushort_t* qp   = (ushort_t*)(ws + QP_OFF);
  ushort_t* kp   = (ushort_t*)(ws + KP_OFF);
  float* ctx     = (float*)(ws + CTX_OFF);
  float* z       = (float*)(ws + Z_OFF);
  float* rowmax  = (float*)(ws + RMAX_OFF);
  float* gmax    = (float*)(ws + GMAX_OFF);

  k_qproj2  <<<NROWS/256, 256, 0, stream>>>(q, proj, qp);
  k_kmax2   <<<NROWS/256, 256, 0, stream>>>(k, proj, rowmax);
  k_gmax    <<<1, 256, 0, stream>>>(rowmax, gmax);
  k_kproj2  <<<NROWS/256, 256, 0, stream>>>(k, proj, gmax, kp);
  k_chunksum<<<NBH*NCH, 256, 0, stream>>>(kp, v, ctx, z);
  k_prefix_ctx<<<NBH*67, 256, 0, stream>>>(ctx);
  k_prefix_z<<<NBH, 256, 0, stream>>>(z);
  k_output  <<<NBH*NCH, 256, 0, stream>>>(qp, kp, v, ctx, z, out);
}

// Round 3
// 574.844 us; speedup vs baseline: 6.9950x; 2.2719x over previous
//
#include <hip/hip_runtime.h>

#define BB 4
#define HH 8
#define NSEQ 4096
#define DD 64
#define MM 266
#define CCH 128
#define NCH 32
#define NBH (BB*HH)
#define NROWS (NBH*NSEQ)

#define NORMALIZER 0.35355339059327373f
#define DIAGF 0.0625f
#define RATIO 0.0613140017f
#define KEPS 1e-4f

typedef unsigned short ushort_t;
typedef unsigned int uint_t;

typedef __attribute__((ext_vector_type(8))) short bf16x8;
typedef __attribute__((ext_vector_type(4))) float f32x4;

__device__ __forceinline__ f32x4 mfma16(bf16x8 a, bf16x8 b, f32x4 c){
  return __builtin_amdgcn_mfma_f32_16x16x32_bf16(a, b, c, 0, 0, 0);
}

__device__ __forceinline__ ushort_t f2bf(float x){
  union { float f; uint_t u; } v; v.f = x;
  uint_t r = (v.u + 0x7FFFu + ((v.u >> 16) & 1u)) >> 16;
  return (ushort_t)r;
}
__device__ __forceinline__ float bf2f(ushort_t h){
  union { uint_t u; float f; } v; v.u = ((uint_t)h) << 16;
  return v.f;
}
__device__ __forceinline__ void unpack2(uint_t w, float& lo, float& hi){
  union { uint_t u; float f; } a, b;
  a.u = w << 16; b.u = w & 0xFFFF0000u;
  lo = a.f; hi = b.f;
}

// MFMA fragment load from a row-major LDS tile.
// lane l supplies element [spatial = s0 + (l&15)][k = koff + (l>>4)*8 + j], j=0..7
__device__ __forceinline__ bf16x8 frag_ld(const ushort_t* tile, int stride, int s0, int koff){
  const int l = threadIdx.x & 63;
  return *(const bf16x8*)(tile + (s0 + (l&15))*stride + koff + ((l>>4)<<3));
}

// ---------------- q projection: fused MFMA dash + rowmax + exp ----------------

__global__ __launch_bounds__(256) void k_qproj3(const float* __restrict__ q,
                                                const float* __restrict__ proj,
                                                ushort_t* __restrict__ qp){
  __shared__ __align__(16) ushort_t pjs[272*72];
  __shared__ __align__(16) ushort_t qs[128*72];
  __shared__ float diags[128];
  const int t = threadIdx.x;

  for (int idx=t; idx<272*32; idx+=256){
    int m = idx>>5, dp = (idx&31)*2;
    uint_t w = 0;
    if (m < MM){
      const float2 p2 = *(const float2*)(proj + (size_t)m*DD + dp);
      w = (uint_t)f2bf(p2.x) | ((uint_t)f2bf(p2.y)<<16);
    }
    *(uint_t*)(pjs + m*72 + dp) = w;
  }
  {
    const int row = t>>1, half = t&1;
    const float2* qr = (const float2*)(q + ((size_t)blockIdx.x*128 + row)*DD + half*32);
    float ss = 0.f;
    #pragma unroll
    for (int i=0;i<16;++i){
      float2 a = qr[i];
      ss += a.x*a.x + a.y*a.y;
      uint_t w = (uint_t)f2bf(a.x*NORMALIZER) | ((uint_t)f2bf(a.y*NORMALIZER)<<16);
      *(uint_t*)(qs + row*72 + half*32 + i*2) = w;
    }
    ss += __shfl_xor(ss, 1);
    if (half==0) diags[row] = ss*DIAGF;
  }
  __syncthreads();

  const int l = t&63, wv = t>>6;
  const int wr0 = wv*32;
  float rmax[2][4];
  #pragma unroll
  for (int rt=0;rt<2;++rt){ rmax[rt][0]=-3e38f; rmax[rt][1]=-3e38f; rmax[rt][2]=-3e38f; rmax[rt][3]=-3e38f; }

  for (int mt=0; mt<17; ++mt){
    bf16x8 b0 = frag_ld(pjs, 72, mt*16, 0);
    bf16x8 b1 = frag_ld(pjs, 72, mt*16, 32);
    const bool valid = (mt<16) || ((l&15) < 10);
    #pragma unroll
    for (int rt=0;rt<2;++rt){
      bf16x8 a0 = frag_ld(qs, 72, wr0+rt*16, 0);
      bf16x8 a1 = frag_ld(qs, 72, wr0+rt*16, 32);
      f32x4 acc = {0.f,0.f,0.f,0.f};
      acc = mfma16(a0, b0, acc);
      acc = mfma16(a1, b1, acc);
      #pragma unroll
      for (int r=0;r<4;++r){
        float vv = valid ? acc[r] : -3e38f;
        rmax[rt][r] = fmaxf(rmax[rt][r], vv);
      }
    }
  }
  #pragma unroll
  for (int rt=0;rt<2;++rt){
    #pragma unroll
    for (int r=0;r<4;++r){
      float m = rmax[rt][r];
      m = fmaxf(m, __shfl_xor(m,1)); m = fmaxf(m, __shfl_xor(m,2));
      m = fmaxf(m, __shfl_xor(m,4)); m = fmaxf(m, __shfl_xor(m,8));
      rmax[rt][r] = m;
    }
  }
  float sub[2][4];
  #pragma unroll
  for (int rt=0;rt<2;++rt){
    #pragma unroll
    for (int r=0;r<4;++r)
      sub[rt][r] = diags[wr0 + rt*16 + ((l>>4)<<2) + r] + rmax[rt][r];
  }

  const size_t growb = (size_t)blockIdx.x*128;
  for (int mt=0; mt<17; ++mt){
    bf16x8 b0 = frag_ld(pjs, 72, mt*16, 0);
    bf16x8 b1 = frag_ld(pjs, 72, mt*16, 32);
    const int m = mt*16 + (l&15);
    #pragma unroll
    for (int rt=0;rt<2;++rt){
      bf16x8 a0 = frag_ld(qs, 72, wr0+rt*16, 0);
      bf16x8 a1 = frag_ld(qs, 72, wr0+rt*16, 32);
      f32x4 acc = {0.f,0.f,0.f,0.f};
      acc = mfma16(a0, b0, acc);
      acc = mfma16(a1, b1, acc);
      if (m < MM){
        #pragma unroll
        for (int r=0;r<4;++r){
          float e = RATIO*(__expf(acc[r]-sub[rt][r]) + KEPS);
          qp[(growb + wr0 + rt*16 + ((l>>4)<<2) + r)*MM + m] = f2bf(e);
        }
      }
    }
  }
}

// ---------------- k rowmax (MFMA dash, max only) ----------------

__global__ __launch_bounds__(256) void k_kmax3(const float* __restrict__ k,
                                               const float* __restrict__ proj,
                                               float* __restrict__ rowmax){
  __shared__ __align__(16) ushort_t pjs[272*72];
  __shared__ __align__(16) ushort_t qs[128*72];
  const int t = threadIdx.x;
  for (int idx=t; idx<272*32; idx+=256){
    int m = idx>>5, dp = (idx&31)*2;
    uint_t w = 0;
    if (m < MM){
      const float2 p2 = *(const float2*)(proj + (size_t)m*DD + dp);
      w = (uint_t)f2bf(p2.x) | ((uint_t)f2bf(p2.y)<<16);
    }
    *(uint_t*)(pjs + m*72 + dp) = w;
  }
  {
    const int row = t>>1, half = t&1;
    const float2* kr = (const float2*)(k + ((size_t)blockIdx.x*128 + row)*DD + half*32);
    #pragma unroll
    for (int i=0;i<16;++i){
      float2 a = kr[i];
      uint_t w = (uint_t)f2bf(a.x*NORMALIZER) | ((uint_t)f2bf(a.y*NORMALIZER)<<16);
      *(uint_t*)(qs + row*72 + half*32 + i*2) = w;
    }
  }
  __syncthreads();

  const int l = t&63, wv = t>>6;
  const int wr0 = wv*32;
  float rmax[2][4];
  #pragma unroll
  for (int rt=0;rt<2;++rt){ rmax[rt][0]=-3e38f; rmax[rt][1]=-3e38f; rmax[rt][2]=-3e38f; rmax[rt][3]=-3e38f; }

  for (int mt=0; mt<17; ++mt){
    bf16x8 b0 = frag_ld(pjs, 72, mt*16, 0);
    bf16x8 b1 = frag_ld(pjs, 72, mt*16, 32);
    const bool valid = (mt<16) || ((l&15) < 10);
    #pragma unroll
    for (int rt=0;rt<2;++rt){
      bf16x8 a0 = frag_ld(qs, 72, wr0+rt*16, 0);
      bf16x8 a1 = frag_ld(qs, 72, wr0+rt*16, 32);
      f32x4 acc = {0.f,0.f,0.f,0.f};
      acc = mfma16(a0, b0, acc);
      acc = mfma16(a1, b1, acc);
      #pragma unroll
      for (int r=0;r<4;++r){
        float vv = valid ? acc[r] : -3e38f;
        rmax[rt][r] = fmaxf(rmax[rt][r], vv);
      }
    }
  }
  #pragma unroll
  for (int rt=0;rt<2;++rt){
    #pragma unroll
    for (int r=0;r<4;++r){
      float m = rmax[rt][r];
      m = fmaxf(m, __shfl_xor(m,1)); m = fmaxf(m, __shfl_xor(m,2));
      m = fmaxf(m, __shfl_xor(m,4)); m = fmaxf(m, __shfl_xor(m,8));
      rmax[rt][r] = m;
    }
  }
  if ((l&15)==0){
    const size_t growb = (size_t)blockIdx.x*128;
    #pragma unroll
    for (int rt=0;rt<2;++rt){
      #pragma unroll
      for (int r=0;r<4;++r)
        rowmax[growb + wr0 + rt*16 + ((l>>4)<<2) + r] = rmax[rt][r];
    }
  }
}

__global__ __launch_bounds__(256) void k_gmax(const float* __restrict__ rowmax,
                                              float* __restrict__ gmax){
  __shared__ float s[4];
  int t = threadIdx.x;
  float m = -1e30f;
  for (int i=t;i<NROWS;i+=256) m = fmaxf(m, rowmax[i]);
  #pragma unroll
  for (int off=32; off>0; off>>=1) m = fmaxf(m, __shfl_xor(m, off));
  if ((t&63)==0) s[t>>6] = m;
  __syncthreads();
  if (t==0) gmax[0] = fmaxf(fmaxf(s[0],s[1]), fmaxf(s[2],s[3]));
}

// ---------------- k projection finalize (MFMA dash + exp, global stab) ----------------

__global__ __launch_bounds__(256) void k_kproj3(const float* __restrict__ k,
                                                const float* __restrict__ proj,
                                                const float* __restrict__ gmax,
                                                ushort_t* __restrict__ kp){
  __shared__ __align__(16) ushort_t pjs[272*72];
  __shared__ __align__(16) ushort_t qs[128*72];
  __shared__ float diags[128];
  const int t = threadIdx.x;
  for (int idx=t; idx<272*32; idx+=256){
    int m = idx>>5, dp = (idx&31)*2;
    uint_t w = 0;
    if (m < MM){
      const float2 p2 = *(const float2*)(proj + (size_t)m*DD + dp);
      w = (uint_t)f2bf(p2.x) | ((uint_t)f2bf(p2.y)<<16);
    }
    *(uint_t*)(pjs + m*72 + dp) = w;
  }
  {
    const int row = t>>1, half = t&1;
    const float2* kr = (const float2*)(k + ((size_t)blockIdx.x*128 + row)*DD + half*32);
    float ss = 0.f;
    #pragma unroll
    for (int i=0;i<16;++i){
      float2 a = kr[i];
      ss += a.x*a.x + a.y*a.y;
      uint_t w = (uint_t)f2bf(a.x*NORMALIZER) | ((uint_t)f2bf(a.y*NORMALIZER)<<16);
      *(uint_t*)(qs + row*72 + half*32 + i*2) = w;
    }
    ss += __shfl_xor(ss, 1);
    if (half==0) diags[row] = ss*DIAGF;
  }
  __syncthreads();

  const float gm = gmax[0];
  const int l = t&63, wv = t>>6;
  const int wr0 = wv*32;
  float sub[2][4];
  #pragma unroll
  for (int rt=0;rt<2;++rt){
    #pragma unroll
    for (int r=0;r<4;++r)
      sub[rt][r] = diags[wr0 + rt*16 + ((l>>4)<<2) + r] + gm;
  }
  const size_t growb = (size_t)blockIdx.x*128;
  for (int mt=0; mt<17; ++mt){
    bf16x8 b0 = frag_ld(pjs, 72, mt*16, 0);
    bf16x8 b1 = frag_ld(pjs, 72, mt*16, 32);
    const int m = mt*16 + (l&15);
    #pragma unroll
    for (int rt=0;rt<2;++rt){
      bf16x8 a0 = frag_ld(qs, 72, wr0+rt*16, 0);
      bf16x8 a1 = frag_ld(qs, 72, wr0+rt*16, 32);
      f32x4 acc = {0.f,0.f,0.f,0.f};
      acc = mfma16(a0, b0, acc);
      acc = mfma16(a1, b1, acc);
      if (m < MM){
        #pragma unroll
        for (int r=0;r<4;++r){
          float e = RATIO*(__expf(acc[r]-sub[rt][r]) + KEPS);
          kp[(growb + wr0 + rt*16 + ((l>>4)<<2) + r)*MM + m] = f2bf(e);
        }
      }
    }
  }
}

// ---------------- chunk sums: CTX_c = kp^T v, z_c = colsum(kp) (VALU, unchanged) ----------------

__global__ __launch_bounds__(256) void k_chunksum(const ushort_t* __restrict__ kp,
                                                  const float* __restrict__ v,
                                                  float* __restrict__ ctx,
                                                  float* __restrict__ z){
  __shared__ float v_s[CCH][DD];
  __shared__ ushort_t kp_s[32][272];
  const int blk = blockIdx.x, bh = blk>>5, ch = blk&31;
  const int t = threadIdx.x, e = t&63, g = t>>6;
  const int row0 = ch*CCH;
  const float* vg = v + (size_t)bh*NSEQ*DD + (size_t)row0*DD;
  for (int idx=t; idx<CCH*DD; idx+=256) v_s[idx>>6][idx&63] = vg[idx];
  float acc[17][4];
  #pragma unroll
  for (int j=0;j<17;++j){ acc[j][0]=0.f; acc[j][1]=0.f; acc[j][2]=0.f; acc[j][3]=0.f; }
  float zac1 = 0.f, zac2 = 0.f;
  const bool has2 = (256 + t) < MM;
  const ushort_t* kg = kp + (size_t)bh*NSEQ*MM + (size_t)row0*MM;
  for (int is=0; is<4; ++is){
    __syncthreads();
    for (int idx=t; idx<32*272; idx+=256){
      int r = idx/272, c2 = idx - r*272;
      kp_s[r][c2] = (c2<MM) ? kg[(size_t)(is*32+r)*MM + c2] : (ushort_t)0;
    }
    __syncthreads();
    for (int il=0; il<32; ++il){
      float vv = v_s[is*32+il][e];
      #pragma unroll
      for (int j=0;j<17;++j){
        uint2 w = *(const uint2*)(&kp_s[il][16*j + 4*g]);
        float f0,f1,f2,f3;
        unpack2(w.x, f0, f1); unpack2(w.y, f2, f3);
        acc[j][0] += f0*vv; acc[j][1] += f1*vv; acc[j][2] += f2*vv; acc[j][3] += f3*vv;
      }
    }
    {
      float s1 = 0.f, s2 = 0.f;
      for (int r=0;r<32;++r){
        s1 += bf2f(kp_s[r][t]);
        if (has2) s2 += bf2f(kp_s[r][256+t]);
      }
      zac1 += s1; if (has2) zac2 += s2;
    }
  }
  float* cg = ctx + (size_t)blk*MM*DD;
  #pragma unroll
  for (int j=0;j<17;++j){
    #pragma unroll
    for (int p=0;p<4;++p){
      int m = 16*j + 4*g + p;
      if (m < MM) cg[(size_t)m*DD + e] = acc[j][p];
    }
  }
  float* zgo = z + (size_t)blk*MM;
  zgo[t] = zac1;
  if (has2) zgo[256+t] = zac2;
}

// ---------------- exclusive prefix over chunks (unchanged) ----------------

__global__ __launch_bounds__(256) void k_prefix_ctx(float* __restrict__ ctx){
  int blk = blockIdx.x; int bh = blk/67, mg = blk%67;
  int t = threadIdx.x; int mo = t>>6, e = t&63;
  int m = mg*4 + mo;
  if (m >= MM) return;
  size_t base = (size_t)bh*NCH*MM*DD + (size_t)m*DD + e;
  float run = 0.f;
  for (int c=0;c<NCH;++c){
    size_t idx = base + (size_t)c*MM*DD;
    float cur = ctx[idx]; ctx[idx] = run; run += cur;
  }
}

__global__ __launch_bounds__(256) void k_prefix_z(float* __restrict__ z){
  int bh = blockIdx.x, t = threadIdx.x;
  size_t base = (size_t)bh*NCH*MM;
  float run1 = 0.f, run2 = 0.f;
  bool has2 = (256+t) < MM;
  for (int c=0;c<NCH;++c){
    size_t o = base + (size_t)c*MM;
    float c1 = z[o+t]; z[o+t] = run1; run1 += c1;
    if (has2){ float c2 = z[o+256+t]; z[o+256+t] = run2; run2 += c2; }
  }
}

// ---------------- per-chunk output (MFMA) ----------------

__global__ __launch_bounds__(256) void k_output4(const ushort_t* __restrict__ qp,
                                                 const ushort_t* __restrict__ kp,
                                                 const float* __restrict__ v,
                                                 const float* __restrict__ ctx,
                                                 const float* __restrict__ z,
                                                 float* __restrict__ out){
  __shared__ __align__(16) char lds[65280];
  ushort_t* qs   = (ushort_t*)lds;            // [128][72]  18,432 B
  ushort_t* kps  = (ushort_t*)(lds + 18432);  // [128][72]  18,432 B
  ushort_t* Ps   = (ushort_t*)lds;            // [128][136] 34,816 B (aliases qs+kps)
  ushort_t* vT   = (ushort_t*)(lds + 36864);  // [64][136]  17,408 B
  ushort_t* ctxT = (ushort_t*)(lds + 54272);  // [64][72]    9,216 B
  float*    zs   = (float*)(lds + 63488);     // [320]       1,280 B
  float*    Drow = (float*)(lds + 64768);     // [128]         512 B

  const int blk = blockIdx.x, bh = blk>>5, ch = blk&31;
  const int t = threadIdx.x, l = t&63, wv = t>>6;
  const int row0 = ch*CCH;
  const int wr0 = wv*32;

  const ushort_t* qg = qp + (size_t)(bh*NSEQ + row0)*MM;
  const ushort_t* kg = kp + (size_t)(bh*NSEQ + row0)*MM;
  const float*    vg = v  + (size_t)(bh*NSEQ + row0)*DD;
  const float*  ctxg = ctx + (size_t)blk*MM*DD;
  const float*    zg = z  + (size_t)blk*MM;

  // stage V transposed (bf16)
  for (int idx=t; idx<CCH*DD; idx+=256){
    int e = idx&63, kk = idx>>6;
    vT[e*136 + kk] = f2bf(vg[(size_t)kk*DD + e]);
  }

  // ---- phase A: S = qp kp^T, K tiles of 64 over m ----
  f32x4 acc[2][8];
  #pragma unroll
  for (int rt=0;rt<2;++rt)
    #pragma unroll
    for (int ct=0;ct<8;++ct) acc[rt][ct] = (f32x4){0.f,0.f,0.f,0.f};

  for (int mt=0; mt<5; ++mt){
    for (int idx=t; idx<128*32; idx+=256){
      int row = idx>>5, m = mt*64 + ((idx&31)<<1);
      uint_t wq = 0, wk = 0;
      if (m < MM){
        wq = *(const uint_t*)(qg + (size_t)row*MM + m);
        wk = *(const uint_t*)(kg + (size_t)row*MM + m);
      }
      *(uint_t*)(qs  + row*72 + (m - mt*64)) = wq;
      *(uint_t*)(kps + row*72 + (m - mt*64)) = wk;
    }
    __syncthreads();
    bf16x8 aq[2][2];
    #pragma unroll
    for (int rt=0;rt<2;++rt){
      aq[rt][0] = frag_ld(qs, 72, wr0+rt*16, 0);
      aq[rt][1] = frag_ld(qs, 72, wr0+rt*16, 32);
    }
    #pragma unroll
    for (int ct=0;ct<8;++ct){
      bf16x8 b0 = frag_ld(kps, 72, ct*16, 0);
      bf16x8 b1 = frag_ld(kps, 72, ct*16, 32);
      #pragma unroll
      for (int rt=0;rt<2;++rt){
        acc[rt][ct] = mfma16(aq[rt][0], b0, acc[rt][ct]);
        acc[rt][ct] = mfma16(aq[rt][1], b1, acc[rt][ct]);
      }
    }
    __syncthreads();
  }

  // ---- mask + row-sum + write P (bf16) to LDS ----
  float ds[2][4];
  #pragma unroll
  for (int rt=0;rt<2;++rt){ ds[rt][0]=0.f; ds[rt][1]=0.f; ds[rt][2]=0.f; ds[rt][3]=0.f; }
  #pragma unroll
  for (int rt=0;rt<2;++rt){
    #pragma unroll
    for (int ct=0;ct<8;++ct){
      #pragma unroll
      for (int r=0;r<4;++r){
        int i = wr0 + rt*16 + ((l>>4)<<2) + r;
        int j = ct*16 + (l&15);
        float m = (j <= i) ? acc[rt][ct][r] : 0.f;
        acc[rt][ct][r] = m;
        ds[rt][r] += m;
      }
    }
  }
  // (barrier already passed after last k-tile; safe to overwrite qs/kps region)
  #pragma unroll
  for (int rt=0;rt<2;++rt){
    #pragma unroll
    for (int ct=0;ct<8;++ct){
      #pragma unroll
      for (int r=0;r<4;++r){
        int i = wr0 + rt*16 + ((l>>4)<<2) + r;
        Ps[i*136 + ct*16 + (l&15)] = f2bf(acc[rt][ct][r]);
      }
    }
  }
  #pragma unroll
  for (int rt=0;rt<2;++rt){
    #pragma unroll
    for (int r=0;r<4;++r){
      float d = ds[rt][r];
      d += __shfl_xor(d,1); d += __shfl_xor(d,2); d += __shfl_xor(d,4); d += __shfl_xor(d,8);
      if ((l&15)==0) Drow[wr0 + rt*16 + ((l>>4)<<2) + r] = d;
    }
  }
  __syncthreads();

  // ---- PV: out1 = P V ----
  f32x4 oacc[2][4];
  #pragma unroll
  for (int rt=0;rt<2;++rt)
    #pragma unroll
    for (int et=0;et<4;++et) oacc[rt][et] = (f32x4){0.f,0.f,0.f,0.f};

  #pragma unroll
  for (int kt=0;kt<4;++kt){
    bf16x8 ap[2];
    #pragma unroll
    for (int rt=0;rt<2;++rt) ap[rt] = frag_ld(Ps, 136, wr0+rt*16, kt*32);
    #pragma unroll
    for (int et=0;et<4;++et){
      bf16x8 bv = frag_ld(vT, 136, et*16, kt*32);
      #pragma unroll
      for (int rt=0;rt<2;++rt) oacc[rt][et] = mfma16(ap[rt], bv, oacc[rt][et]);
    }
  }
  __syncthreads();

  // ---- phase 2: out += qp CTXp ; D += qp . zp ----
  for (int i=t;i<320;i+=256) zs[i] = (i<MM) ? zg[i] : 0.f;
  float Dz = 0.f;
  const int rD = t>>1, hD = t&1;
  for (int mt=0; mt<5; ++mt){
    for (int idx=t; idx<128*32; idx+=256){
      int row = idx>>5, m = mt*64 + ((idx&31)<<1);
      uint_t wq = 0;
      if (m < MM) wq = *(const uint_t*)(qg + (size_t)row*MM + m);
      *(uint_t*)(qs + row*72 + (m - mt*64)) = wq;
    }
    for (int idx=t; idx<64*64; idx+=256){
      int e = idx&63, mm = idx>>6;
      int m = mt*64 + mm;
      ctxT[e*72 + mm] = (m<MM) ? f2bf(ctxg[(size_t)m*DD + e]) : (ushort_t)0;
    }
    __syncthreads();
    bf16x8 aq[2][2];
    #pragma unroll
    for (int rt=0;rt<2;++rt){
      aq[rt][0] = frag_ld(qs, 72, wr0+rt*16, 0);
      aq[rt][1] = frag_ld(qs, 72, wr0+rt*16, 32);
    }
    #pragma unroll
    for (int et=0;et<4;++et){
      bf16x8 b0 = frag_ld(ctxT, 72, et*16, 0);
      bf16x8 b1 = frag_ld(ctxT, 72, et*16, 32);
      #pragma unroll
      for (int rt=0;rt<2;++rt){
        oacc[rt][et] = mfma16(aq[rt][0], b0, oacc[rt][et]);
        oacc[rt][et] = mfma16(aq[rt][1], b1, oacc[rt][et]);
      }
    }
    {
      float s = 0.f;
      const int base = rD*72 + hD*32;
      for (int mm=0;mm<32;++mm) s += bf2f(qs[base + mm]) * zs[mt*64 + hD*32 + mm];
      Dz += s;
    }
    __syncthreads();
  }
  Dz += __shfl_xor(Dz, 1);
  if (hD==0) Drow[rD] += Dz;
  __syncthreads();

  // ---- epilogue ----
  float* og = out + (size_t)(bh*NSEQ + row0)*DD;
  #pragma unroll
  for (int rt=0;rt<2;++rt){
    #pragma unroll
    for (int r=0;r<4;++r){
      int i = wr0 + rt*16 + ((l>>4)<<2) + r;
      float dinv = 1.0f / Drow[i];
      #pragma unroll
      for (int et=0;et<4;++et)
        og[(size_t)i*DD + et*16 + (l&15)] = oacc[rt][et][r] * dinv;
    }
  }
}

// ---------------- launch ----------------

extern "C" void kernel_launch(void* const* d_in, const int* in_sizes, int n_in,
                              void* d_out, int out_size, void* d_ws, size_t ws_size,
                              hipStream_t stream) {
  const float* q    = (const float*)d_in[0];
  const float* k    = (const float*)d_in[1];
  const float* v    = (const float*)d_in[2];
  const float* proj = (const float*)d_in[3];
  float* out = (float*)d_out;
  char* ws = (char*)d_ws;

  const size_t QP_OFF   = 0;
  const size_t KP_OFF   = 69730304ull;
  const size_t CTX_OFF  = 139460608ull;
  const size_t Z_OFF    = 209190912ull;
  const size_t RMAX_OFF = 210280448ull;
  const size_t GMAX_OFF = 210804736ull;
  if (ws_size < 210805000ull) return;

  ushort_t* qp   = (ushort_t*)(ws + QP_OFF);
  ushort_t* kp   = (ushort_t*)(ws + KP_OFF);
  float* ctx     = (float*)(ws + CTX_OFF);
  float* z       = (float*)(ws + Z_OFF);
  float* rowmax  = (float*)(ws + RMAX_OFF);
  float* gmax    = (float*)(ws + GMAX_OFF);

  k_qproj3  <<<NROWS/128, 256, 0, stream>>>(q, proj, qp);
  k_kmax3   <<<NROWS/128, 256, 0, stream>>>(k, proj, rowmax);
  k_gmax    <<<1, 256, 0, stream>>>(rowmax, gmax);
  k_kproj3  <<<NROWS/128, 256, 0, stream>>>(k, proj, gmax, kp);
  k_chunksum<<<NBH*NCH, 256, 0, stream>>>(kp, v, ctx, z);
  k_prefix_ctx<<<NBH*67, 256, 0, stream>>>(ctx);
  k_prefix_z<<<NBH, 256, 0, stream>>>(z);
  k_output4 <<<NBH*NCH, 256, 0, stream>>>(qp, kp, v, ctx, z, out);
}

// Round 4
// 536.654 us; speedup vs baseline: 7.4927x; 1.0712x over previous
//
#include <hip/hip_runtime.h>

#define BB 4
#define HH 8
#define NSEQ 4096
#define DD 64
#define MM 266
#define CCH 128
#define NCH 32
#define NBH (BB*HH)
#define NROWS (NBH*NSEQ)

#define NORMALIZER 0.35355339059327373f
#define DIAGF 0.0625f
#define RATIO 0.0613140017f
#define KEPS 1e-4f

typedef unsigned short ushort_t;
typedef unsigned int uint_t;

typedef __attribute__((ext_vector_type(8))) short bf16x8;
typedef __attribute__((ext_vector_type(4))) float f32x4;

__device__ __forceinline__ f32x4 mfma16(bf16x8 a, bf16x8 b, f32x4 c){
  return __builtin_amdgcn_mfma_f32_16x16x32_bf16(a, b, c, 0, 0, 0);
}

__device__ __forceinline__ ushort_t f2bf(float x){
  union { float f; uint_t u; } v; v.f = x;
  uint_t r = (v.u + 0x7FFFu + ((v.u >> 16) & 1u)) >> 16;
  return (ushort_t)r;
}
__device__ __forceinline__ float bf2f(ushort_t h){
  union { uint_t u; float f; } v; v.u = ((uint_t)h) << 16;
  return v.f;
}

// MFMA fragment load from a row-major LDS tile.
// lane l supplies element [spatial = s0 + (l&15)][k = koff + (l>>4)*8 + j], j=0..7
__device__ __forceinline__ bf16x8 frag_ld(const ushort_t* tile, int stride, int s0, int koff){
  const int l = threadIdx.x & 63;
  return *(const bf16x8*)(tile + (s0 + (l&15))*stride + koff + ((l>>4)<<3));
}

// ---------------- q projection: fused MFMA dash + rowmax + exp ----------------

__global__ __launch_bounds__(256) void k_qproj3(const float* __restrict__ q,
                                                const float* __restrict__ proj,
                                                ushort_t* __restrict__ qp){
  __shared__ __align__(16) ushort_t pjs[272*72];
  __shared__ __align__(16) ushort_t qs[128*72];
  __shared__ float diags[128];
  const int t = threadIdx.x;

  for (int idx=t; idx<272*32; idx+=256){
    int m = idx>>5, dp = (idx&31)*2;
    uint_t w = 0;
    if (m < MM){
      const float2 p2 = *(const float2*)(proj + (size_t)m*DD + dp);
      w = (uint_t)f2bf(p2.x) | ((uint_t)f2bf(p2.y)<<16);
    }
    *(uint_t*)(pjs + m*72 + dp) = w;
  }
  {
    const int row = t>>1, half = t&1;
    const float2* qr = (const float2*)(q + ((size_t)blockIdx.x*128 + row)*DD + half*32);
    float ss = 0.f;
    #pragma unroll
    for (int i=0;i<16;++i){
      float2 a = qr[i];
      ss += a.x*a.x + a.y*a.y;
      uint_t w = (uint_t)f2bf(a.x*NORMALIZER) | ((uint_t)f2bf(a.y*NORMALIZER)<<16);
      *(uint_t*)(qs + row*72 + half*32 + i*2) = w;
    }
    ss += __shfl_xor(ss, 1);
    if (half==0) diags[row] = ss*DIAGF;
  }
  __syncthreads();

  const int l = t&63, wv = t>>6;
  const int wr0 = wv*32;
  float rmax[2][4];
  #pragma unroll
  for (int rt=0;rt<2;++rt){ rmax[rt][0]=-3e38f; rmax[rt][1]=-3e38f; rmax[rt][2]=-3e38f; rmax[rt][3]=-3e38f; }

  for (int mt=0; mt<17; ++mt){
    bf16x8 b0 = frag_ld(pjs, 72, mt*16, 0);
    bf16x8 b1 = frag_ld(pjs, 72, mt*16, 32);
    const bool valid = (mt<16) || ((l&15) < 10);
    #pragma unroll
    for (int rt=0;rt<2;++rt){
      bf16x8 a0 = frag_ld(qs, 72, wr0+rt*16, 0);
      bf16x8 a1 = frag_ld(qs, 72, wr0+rt*16, 32);
      f32x4 acc = {0.f,0.f,0.f,0.f};
      acc = mfma16(a0, b0, acc);
      acc = mfma16(a1, b1, acc);
      #pragma unroll
      for (int r=0;r<4;++r){
        float vv = valid ? acc[r] : -3e38f;
        rmax[rt][r] = fmaxf(rmax[rt][r], vv);
      }
    }
  }
  #pragma unroll
  for (int rt=0;rt<2;++rt){
    #pragma unroll
    for (int r=0;r<4;++r){
      float m = rmax[rt][r];
      m = fmaxf(m, __shfl_xor(m,1)); m = fmaxf(m, __shfl_xor(m,2));
      m = fmaxf(m, __shfl_xor(m,4)); m = fmaxf(m, __shfl_xor(m,8));
      rmax[rt][r] = m;
    }
  }
  float sub[2][4];
  #pragma unroll
  for (int rt=0;rt<2;++rt){
    #pragma unroll
    for (int r=0;r<4;++r)
      sub[rt][r] = diags[wr0 + rt*16 + ((l>>4)<<2) + r] + rmax[rt][r];
  }

  const size_t growb = (size_t)blockIdx.x*128;
  for (int mt=0; mt<17; ++mt){
    bf16x8 b0 = frag_ld(pjs, 72, mt*16, 0);
    bf16x8 b1 = frag_ld(pjs, 72, mt*16, 32);
    const int m = mt*16 + (l&15);
    #pragma unroll
    for (int rt=0;rt<2;++rt){
      bf16x8 a0 = frag_ld(qs, 72, wr0+rt*16, 0);
      bf16x8 a1 = frag_ld(qs, 72, wr0+rt*16, 32);
      f32x4 acc = {0.f,0.f,0.f,0.f};
      acc = mfma16(a0, b0, acc);
      acc = mfma16(a1, b1, acc);
      if (m < MM){
        #pragma unroll
        for (int r=0;r<4;++r){
          float e = RATIO*(__expf(acc[r]-sub[rt][r]) + KEPS);
          qp[(growb + wr0 + rt*16 + ((l>>4)<<2) + r)*MM + m] = f2bf(e);
        }
      }
    }
  }
}

// ---------------- k rowmax (MFMA dash, max only) ----------------

__global__ __launch_bounds__(256) void k_kmax3(const float* __restrict__ k,
                                               const float* __restrict__ proj,
                                               float* __restrict__ rowmax){
  __shared__ __align__(16) ushort_t pjs[272*72];
  __shared__ __align__(16) ushort_t qs[128*72];
  const int t = threadIdx.x;
  for (int idx=t; idx<272*32; idx+=256){
    int m = idx>>5, dp = (idx&31)*2;
    uint_t w = 0;
    if (m < MM){
      const float2 p2 = *(const float2*)(proj + (size_t)m*DD + dp);
      w = (uint_t)f2bf(p2.x) | ((uint_t)f2bf(p2.y)<<16);
    }
    *(uint_t*)(pjs + m*72 + dp) = w;
  }
  {
    const int row = t>>1, half = t&1;
    const float2* kr = (const float2*)(k + ((size_t)blockIdx.x*128 + row)*DD + half*32);
    #pragma unroll
    for (int i=0;i<16;++i){
      float2 a = kr[i];
      uint_t w = (uint_t)f2bf(a.x*NORMALIZER) | ((uint_t)f2bf(a.y*NORMALIZER)<<16);
      *(uint_t*)(qs + row*72 + half*32 + i*2) = w;
    }
  }
  __syncthreads();

  const int l = t&63, wv = t>>6;
  const int wr0 = wv*32;
  float rmax[2][4];
  #pragma unroll
  for (int rt=0;rt<2;++rt){ rmax[rt][0]=-3e38f; rmax[rt][1]=-3e38f; rmax[rt][2]=-3e38f; rmax[rt][3]=-3e38f; }

  for (int mt=0; mt<17; ++mt){
    bf16x8 b0 = frag_ld(pjs, 72, mt*16, 0);
    bf16x8 b1 = frag_ld(pjs, 72, mt*16, 32);
    const bool valid = (mt<16) || ((l&15) < 10);
    #pragma unroll
    for (int rt=0;rt<2;++rt){
      bf16x8 a0 = frag_ld(qs, 72, wr0+rt*16, 0);
      bf16x8 a1 = frag_ld(qs, 72, wr0+rt*16, 32);
      f32x4 acc = {0.f,0.f,0.f,0.f};
      acc = mfma16(a0, b0, acc);
      acc = mfma16(a1, b1, acc);
      #pragma unroll
      for (int r=0;r<4;++r){
        float vv = valid ? acc[r] : -3e38f;
        rmax[rt][r] = fmaxf(rmax[rt][r], vv);
      }
    }
  }
  #pragma unroll
  for (int rt=0;rt<2;++rt){
    #pragma unroll
    for (int r=0;r<4;++r){
      float m = rmax[rt][r];
      m = fmaxf(m, __shfl_xor(m,1)); m = fmaxf(m, __shfl_xor(m,2));
      m = fmaxf(m, __shfl_xor(m,4)); m = fmaxf(m, __shfl_xor(m,8));
      rmax[rt][r] = m;
    }
  }
  if ((l&15)==0){
    const size_t growb = (size_t)blockIdx.x*128;
    #pragma unroll
    for (int rt=0;rt<2;++rt){
      #pragma unroll
      for (int r=0;r<4;++r)
        rowmax[growb + wr0 + rt*16 + ((l>>4)<<2) + r] = rmax[rt][r];
    }
  }
}

__global__ __launch_bounds__(256) void k_gmax(const float* __restrict__ rowmax,
                                              float* __restrict__ gmax){
  __shared__ float s[4];
  int t = threadIdx.x;
  float m = -1e30f;
  for (int i=t;i<NROWS;i+=256) m = fmaxf(m, rowmax[i]);
  #pragma unroll
  for (int off=32; off>0; off>>=1) m = fmaxf(m, __shfl_xor(m, off));
  if ((t&63)==0) s[t>>6] = m;
  __syncthreads();
  if (t==0) gmax[0] = fmaxf(fmaxf(s[0],s[1]), fmaxf(s[2],s[3]));
}

// ---------------- k projection finalize (MFMA dash + exp, global stab) ----------------

__global__ __launch_bounds__(256) void k_kproj3(const float* __restrict__ k,
                                                const float* __restrict__ proj,
                                                const float* __restrict__ gmax,
                                                ushort_t* __restrict__ kp){
  __shared__ __align__(16) ushort_t pjs[272*72];
  __shared__ __align__(16) ushort_t qs[128*72];
  __shared__ float diags[128];
  const int t = threadIdx.x;
  for (int idx=t; idx<272*32; idx+=256){
    int m = idx>>5, dp = (idx&31)*2;
    uint_t w = 0;
    if (m < MM){
      const float2 p2 = *(const float2*)(proj + (size_t)m*DD + dp);
      w = (uint_t)f2bf(p2.x) | ((uint_t)f2bf(p2.y)<<16);
    }
    *(uint_t*)(pjs + m*72 + dp) = w;
  }
  {
    const int row = t>>1, half = t&1;
    const float2* kr = (const float2*)(k + ((size_t)blockIdx.x*128 + row)*DD + half*32);
    float ss = 0.f;
    #pragma unroll
    for (int i=0;i<16;++i){
      float2 a = kr[i];
      ss += a.x*a.x + a.y*a.y;
      uint_t w = (uint_t)f2bf(a.x*NORMALIZER) | ((uint_t)f2bf(a.y*NORMALIZER)<<16);
      *(uint_t*)(qs + row*72 + half*32 + i*2) = w;
    }
    ss += __shfl_xor(ss, 1);
    if (half==0) diags[row] = ss*DIAGF;
  }
  __syncthreads();

  const float gm = gmax[0];
  const int l = t&63, wv = t>>6;
  const int wr0 = wv*32;
  float sub[2][4];
  #pragma unroll
  for (int rt=0;rt<2;++rt){
    #pragma unroll
    for (int r=0;r<4;++r)
      sub[rt][r] = diags[wr0 + rt*16 + ((l>>4)<<2) + r] + gm;
  }
  const size_t growb = (size_t)blockIdx.x*128;
  for (int mt=0; mt<17; ++mt){
    bf16x8 b0 = frag_ld(pjs, 72, mt*16, 0);
    bf16x8 b1 = frag_ld(pjs, 72, mt*16, 32);
    const int m = mt*16 + (l&15);
    #pragma unroll
    for (int rt=0;rt<2;++rt){
      bf16x8 a0 = frag_ld(qs, 72, wr0+rt*16, 0);
      bf16x8 a1 = frag_ld(qs, 72, wr0+rt*16, 32);
      f32x4 acc = {0.f,0.f,0.f,0.f};
      acc = mfma16(a0, b0, acc);
      acc = mfma16(a1, b1, acc);
      if (m < MM){
        #pragma unroll
        for (int r=0;r<4;++r){
          float e = RATIO*(__expf(acc[r]-sub[rt][r]) + KEPS);
          kp[(growb + wr0 + rt*16 + ((l>>4)<<2) + r)*MM + m] = f2bf(e);
        }
      }
    }
  }
}

// ---------------- chunk sums via MFMA: CTX_c = kp^T v, z_c = colsum(kp) ----------------

__global__ __launch_bounds__(256) void k_chunksum2(const ushort_t* __restrict__ kp,
                                                   const float* __restrict__ v,
                                                   float* __restrict__ ctx,
                                                   float* __restrict__ z){
  __shared__ __align__(16) ushort_t kpT[272*34];  // [m][row-subtile 32], 18,496 B
  __shared__ __align__(16) ushort_t vT[64*136];   // [e][row 128], 17,408 B
  const int blk = blockIdx.x, bh = blk>>5, ch = blk&31;
  const int t = threadIdx.x, l = t&63, wv = t>>6;
  const int row0 = ch*CCH;
  const ushort_t* kg = kp + (size_t)(bh*NSEQ + row0)*MM;
  const float*    vg = v  + (size_t)(bh*NSEQ + row0)*DD;

  // stage V transposed (bf16)
  for (int idx=t; idx<CCH*DD; idx+=256){
    int e = idx&63, r = idx>>6;
    vT[e*136 + r] = f2bf(vg[(size_t)r*DD + e]);
  }

  f32x4 acc[17];
  #pragma unroll
  for (int i=0;i<17;++i) acc[i] = (f32x4){0.f,0.f,0.f,0.f};
  float zacc = 0.f, zacc2 = 0.f;
  const bool hasz2 = (256 + t) < MM;

  for (int ks=0; ks<4; ++ks){
    __syncthreads();   // protect kpT from previous iteration's readers (and order vT on ks=0)
    // stage kp^T for rows ks*32..+31: wave wv covers 8 rows, lanes walk m
    for (int rr=0; rr<8; ++rr){
      const int r = wv*8 + rr;
      const ushort_t* src = kg + (size_t)(ks*32 + r)*MM;
      for (int m=l; m<272; m+=64)
        kpT[m*34 + r] = (m < MM) ? src[m] : (ushort_t)0;
    }
    __syncthreads();
    // z partial: thread t sums column m=t (and m=256+t for t<16) over the 32 rows
    {
      float s1 = 0.f, s2 = 0.f;
      #pragma unroll
      for (int r=0;r<32;++r){
        s1 += bf2f(kpT[t*34 + r]);
        if (t < 16) s2 += bf2f(kpT[(256+t)*34 + r]);
      }
      zacc += s1; zacc2 += s2;
    }
    // MFMA: wave wv owns e-tile wv; accumulate all 17 m-tiles
    bf16x8 bv = frag_ld(vT, 136, wv*16, ks*32);
    #pragma unroll
    for (int mt=0; mt<17; ++mt){
      bf16x8 a = frag_ld(kpT, 34, mt*16, 0);
      acc[mt] = mfma16(a, bv, acc[mt]);
    }
  }

  // write CTX: m = mt*16 + (l>>4)*4 + r ; e = wv*16 + (l&15)
  float* cg = ctx + (size_t)blk*MM*DD;
  const int e = wv*16 + (l&15);
  #pragma unroll
  for (int mt=0; mt<17; ++mt){
    #pragma unroll
    for (int r=0;r<4;++r){
      int m = mt*16 + ((l>>4)<<2) + r;
      if (m < MM) cg[(size_t)m*DD + e] = acc[mt][r];
    }
  }
  float* zgo = z + (size_t)blk*MM;
  zgo[t] = zacc;
  if (hasz2) zgo[256+t] = zacc2;
}

// ---------------- exclusive prefix over chunks ----------------

__global__ __launch_bounds__(256) void k_prefix_ctx(float* __restrict__ ctx){
  int blk = blockIdx.x; int bh = blk/67, mg = blk%67;
  int t = threadIdx.x; int mo = t>>6, e = t&63;
  int m = mg*4 + mo;
  if (m >= MM) return;
  size_t base = (size_t)bh*NCH*MM*DD + (size_t)m*DD + e;
  float run = 0.f;
  for (int c=0;c<NCH;++c){
    size_t idx = base + (size_t)c*MM*DD;
    float cur = ctx[idx]; ctx[idx] = run; run += cur;
  }
}

__global__ __launch_bounds__(256) void k_prefix_z(float* __restrict__ z){
  int bh = blockIdx.x, t = threadIdx.x;
  size_t base = (size_t)bh*NCH*MM;
  float run1 = 0.f, run2 = 0.f;
  bool has2 = (256+t) < MM;
  for (int c=0;c<NCH;++c){
    size_t o = base + (size_t)c*MM;
    float c1 = z[o+t]; z[o+t] = run1; run1 += c1;
    if (has2){ float c2 = z[o+256+t]; z[o+256+t] = run2; run2 += c2; }
  }
}

// ---------------- per-chunk output (MFMA, single fused m-loop) ----------------

__global__ __launch_bounds__(256) void k_output5(const ushort_t* __restrict__ qp,
                                                 const ushort_t* __restrict__ kp,
                                                 const float* __restrict__ v,
                                                 const float* __restrict__ ctx,
                                                 const float* __restrict__ z,
                                                 float* __restrict__ out){
  __shared__ __align__(16) char lds[65536];
  ushort_t* qs   = (ushort_t*)lds;            // [128][72]  18,432 B
  ushort_t* kps  = (ushort_t*)(lds + 18432);  // [128][72]  18,432 B
  ushort_t* Ps   = (ushort_t*)lds;            // [128][136] 34,816 B (aliases qs+kps)
  ushort_t* vT   = (ushort_t*)(lds + 36864);  // [64][136]  17,408 B
  ushort_t* ctxT = (ushort_t*)(lds + 54272);  // [64][74]    9,472 B
  float*    zs   = (float*)(lds + 63744);     // [320]       1,280 B
  float*    Drow = (float*)(lds + 65024);     // [128]         512 B

  const int blk = blockIdx.x, bh = blk>>5, ch = blk&31;
  const int t = threadIdx.x, l = t&63, wv = t>>6;
  const int row0 = ch*CCH;
  const int wr0 = wv*32;

  const ushort_t* qg = qp + (size_t)(bh*NSEQ + row0)*MM;
  const ushort_t* kg = kp + (size_t)(bh*NSEQ + row0)*MM;
  const float*    vg = v  + (size_t)(bh*NSEQ + row0)*DD;
  const float*  ctxg = ctx + (size_t)blk*MM*DD;
  const float*    zg = z  + (size_t)blk*MM;

  // stage V transposed (bf16) and z prefix
  for (int idx=t; idx<CCH*DD; idx+=256){
    int e = idx&63, kk = idx>>6;
    vT[e*136 + kk] = f2bf(vg[(size_t)kk*DD + e]);
  }
  for (int i=t;i<320;i+=256) zs[i] = (i<MM) ? zg[i] : 0.f;

  f32x4 acc[2][8];
  f32x4 oacc[2][4];
  #pragma unroll
  for (int rt=0;rt<2;++rt){
    #pragma unroll
    for (int ct=0;ct<8;++ct) acc[rt][ct] = (f32x4){0.f,0.f,0.f,0.f};
    #pragma unroll
    for (int et=0;et<4;++et) oacc[rt][et] = (f32x4){0.f,0.f,0.f,0.f};
  }

  float Dz = 0.f;
  const int rD = t>>1, hD = t&1;

  // ---- fused m-loop: S += qp kp^T ; oacc += qp CTXp ; Dz += qp . zp ----
  for (int mt=0; mt<5; ++mt){
    const int m0 = mt*64;
    for (int idx=t; idx<128*32; idx+=256){
      int row = idx>>5, m = m0 + ((idx&31)<<1);
      uint_t wq = 0, wk = 0;
      if (m < MM){
        wq = *(const uint_t*)(qg + (size_t)row*MM + m);
        wk = *(const uint_t*)(kg + (size_t)row*MM + m);
      }
      *(uint_t*)(qs  + row*72 + (m - m0)) = wq;
      *(uint_t*)(kps + row*72 + (m - m0)) = wk;
    }
    for (int idx=t; idx<64*64; idx+=256){
      int e = idx&63, mm = idx>>6;
      int m = m0 + mm;
      ctxT[e*74 + mm] = (m<MM) ? f2bf(ctxg[(size_t)m*DD + e]) : (ushort_t)0;
    }
    __syncthreads();

    bf16x8 aq[2][2];
    #pragma unroll
    for (int rt=0;rt<2;++rt){
      aq[rt][0] = frag_ld(qs, 72, wr0+rt*16, 0);
      aq[rt][1] = frag_ld(qs, 72, wr0+rt*16, 32);
    }
    #pragma unroll
    for (int ct=0;ct<8;++ct){
      bf16x8 b0 = frag_ld(kps, 72, ct*16, 0);
      bf16x8 b1 = frag_ld(kps, 72, ct*16, 32);
      #pragma unroll
      for (int rt=0;rt<2;++rt){
        acc[rt][ct] = mfma16(aq[rt][0], b0, acc[rt][ct]);
        acc[rt][ct] = mfma16(aq[rt][1], b1, acc[rt][ct]);
      }
    }
    #pragma unroll
    for (int et=0;et<4;++et){
      bf16x8 b0 = frag_ld(ctxT, 74, et*16, 0);
      bf16x8 b1 = frag_ld(ctxT, 74, et*16, 32);
      #pragma unroll
      for (int rt=0;rt<2;++rt){
        oacc[rt][et] = mfma16(aq[rt][0], b0, oacc[rt][et]);
        oacc[rt][et] = mfma16(aq[rt][1], b1, oacc[rt][et]);
      }
    }
    {
      float s = 0.f;
      const int base = rD*72 + hD*32;
      #pragma unroll
      for (int mm=0;mm<32;++mm) s += bf2f(qs[base + mm]) * zs[m0 + hD*32 + mm];
      Dz += s;
    }
    __syncthreads();
  }

  // ---- mask + row-sum + write P (bf16) to LDS (Ps aliases qs/kps) ----
  float ds[2][4];
  #pragma unroll
  for (int rt=0;rt<2;++rt){ ds[rt][0]=0.f; ds[rt][1]=0.f; ds[rt][2]=0.f; ds[rt][3]=0.f; }
  #pragma unroll
  for (int rt=0;rt<2;++rt){
    #pragma unroll
    for (int ct=0;ct<8;++ct){
      #pragma unroll
      for (int r=0;r<4;++r){
        int i = wr0 + rt*16 + ((l>>4)<<2) + r;
        int j = ct*16 + (l&15);
        float m = (j <= i) ? acc[rt][ct][r] : 0.f;
        acc[rt][ct][r] = m;
        ds[rt][r] += m;
      }
    }
  }
  #pragma unroll
  for (int rt=0;rt<2;++rt){
    #pragma unroll
    for (int ct=0;ct<8;++ct){
      #pragma unroll
      for (int r=0;r<4;++r){
        int i = wr0 + rt*16 + ((l>>4)<<2) + r;
        Ps[i*136 + ct*16 + (l&15)] = f2bf(acc[rt][ct][r]);
      }
    }
  }
  #pragma unroll
  for (int rt=0;rt<2;++rt){
    #pragma unroll
    for (int r=0;r<4;++r){
      float d = ds[rt][r];
      d += __shfl_xor(d,1); d += __shfl_xor(d,2); d += __shfl_xor(d,4); d += __shfl_xor(d,8);
      if ((l&15)==0) Drow[wr0 + rt*16 + ((l>>4)<<2) + r] = d;
    }
  }
  __syncthreads();

  // Dz fold-in
  Dz += __shfl_xor(Dz, 1);
  if (hD==0) Drow[rD] += Dz;
  __syncthreads();

  // ---- PV: oacc += P V ----
  #pragma unroll
  for (int kt=0;kt<4;++kt){
    bf16x8 ap[2];
    #pragma unroll
    for (int rt=0;rt<2;++rt) ap[rt] = frag_ld(Ps, 136, wr0+rt*16, kt*32);
    #pragma unroll
    for (int et=0;et<4;++et){
      bf16x8 bv = frag_ld(vT, 136, et*16, kt*32);
      #pragma unroll
      for (int rt=0;rt<2;++rt) oacc[rt][et] = mfma16(ap[rt], bv, oacc[rt][et]);
    }
  }

  // ---- epilogue ----
  float* og = out + (size_t)(bh*NSEQ + row0)*DD;
  #pragma unroll
  for (int rt=0;rt<2;++rt){
    #pragma unroll
    for (int r=0;r<4;++r){
      int i = wr0 + rt*16 + ((l>>4)<<2) + r;
      float dinv = 1.0f / Drow[i];
      #pragma unroll
      for (int et=0;et<4;++et)
        og[(size_t)i*DD + et*16 + (l&15)] = oacc[rt][et][r] * dinv;
    }
  }
}

// ---------------- launch ----------------

extern "C" void kernel_launch(void* const* d_in, const int* in_sizes, int n_in,
                              void* d_out, int out_size, void* d_ws, size_t ws_size,
                              hipStream_t stream) {
  const float* q    = (const float*)d_in[0];
  const float* k    = (const float*)d_in[1];
  const float* v    = (const float*)d_in[2];
  const float* proj = (const float*)d_in[3];
  float* out = (float*)d_out;
  char* ws = (char*)d_ws;

  const size_t QP_OFF   = 0;
  const size_t KP_OFF   = 69730304ull;
  const size_t CTX_OFF  = 139460608ull;
  const size_t Z_OFF    = 209190912ull;
  const size_t RMAX_OFF = 210280448ull;
  const size_t GMAX_OFF = 210804736ull;
  if (ws_size < 210805000ull) return;

  ushort_t* qp   = (ushort_t*)(ws + QP_OFF);
  ushort_t* kp   = (ushort_t*)(ws + KP_OFF);
  float* ctx     = (float*)(ws + CTX_OFF);
  float* z       = (float*)(ws + Z_OFF);
  float* rowmax  = (float*)(ws + RMAX_OFF);
  float* gmax    = (float*)(ws + GMAX_OFF);

  k_qproj3   <<<NROWS/128, 256, 0, stream>>>(q, proj, qp);
  k_kmax3    <<<NROWS/128, 256, 0, stream>>>(k, proj, rowmax);
  k_gmax     <<<1, 256, 0, stream>>>(rowmax, gmax);
  k_kproj3   <<<NROWS/128, 256, 0, stream>>>(k, proj, gmax, kp);
  k_chunksum2<<<NBH*NCH, 256, 0, stream>>>(kp, v, ctx, z);
  k_prefix_ctx<<<NBH*67, 256, 0, stream>>>(ctx);
  k_prefix_z <<<NBH, 256, 0, stream>>>(z);
  k_output5  <<<NBH*NCH, 256, 0, stream>>>(qp, kp, v, ctx, z, out);
}

// Round 5
// 293.804 us; speedup vs baseline: 13.6860x; 1.8266x over previous
//
#include <hip/hip_runtime.h>

#define BB 4
#define HH 8
#define NSEQ 4096
#define DD 64
#define MM 266
#define CCH 128
#define NCH 32
#define NBH (BB*HH)
#define NROWS (NBH*NSEQ)

#define NORMALIZER 0.35355339059327373f
#define DIAGF 0.0625f
#define RATIO 0.0613140017f
#define KEPS 1e-4f
#define SBIAS 4.0f

typedef unsigned short ushort_t;
typedef unsigned int uint_t;

typedef __attribute__((ext_vector_type(8))) short bf16x8;
typedef __attribute__((ext_vector_type(4))) float f32x4;

__device__ __forceinline__ f32x4 mfma16(bf16x8 a, bf16x8 b, f32x4 c){
  return __builtin_amdgcn_mfma_f32_16x16x32_bf16(a, b, c, 0, 0, 0);
}

__device__ __forceinline__ ushort_t f2bf(float x){
  union { float f; uint_t u; } v; v.f = x;
  uint_t r = (v.u + 0x7FFFu + ((v.u >> 16) & 1u)) >> 16;
  return (ushort_t)r;
}
__device__ __forceinline__ float bf2f(ushort_t h){
  union { uint_t u; float f; } v; v.u = ((uint_t)h) << 16;
  return v.f;
}
__device__ __forceinline__ void unpack2(uint_t w, float& lo, float& hi){
  union { uint_t u; float f; } a, b;
  a.u = w << 16; b.u = w & 0xFFFF0000u;
  lo = a.f; hi = b.f;
}

// MFMA fragment load from a row-major LDS tile.
// lane l supplies element [spatial = s0 + (l&15)][k = koff + (l>>4)*8 + j], j=0..7
__device__ __forceinline__ bf16x8 frag_ld(const ushort_t* tile, int stride, int s0, int koff){
  const int l = threadIdx.x & 63;
  return *(const bf16x8*)(tile + (s0 + (l&15))*stride + koff + ((l>>4)<<3));
}

// ---------------- dash kernel: s' = dash - diag + SBIAS (bf16), rowsub = max_m(s')+diag ----------------

__global__ __launch_bounds__(256) void k_dash(const float* __restrict__ x,
                                              const float* __restrict__ proj,
                                              ushort_t* __restrict__ sbuf,
                                              float* __restrict__ rowsub){
  __shared__ __align__(16) ushort_t pjs[272*72];
  __shared__ __align__(16) ushort_t qs[128*72];
  __shared__ float diags[128];
  const int t = threadIdx.x;

  // stage projection (batched, two rounds of 17 independent loads)
  #pragma unroll
  for (int h=0; h<2; ++h){
    float2 pv[17];
    #pragma unroll
    for (int i=0;i<17;++i){
      int idx = t + (h*17+i)*256;
      int m = idx>>5, dp = (idx&31)*2;
      float2 p2 = {0.f,0.f};
      if (m < MM) p2 = *(const float2*)(proj + (size_t)m*DD + dp);
      pv[i] = p2;
    }
    #pragma unroll
    for (int i=0;i<17;++i){
      int idx = t + (h*17+i)*256;
      int m = idx>>5, dp = (idx&31)*2;
      *(uint_t*)(pjs + m*72 + dp) = (uint_t)f2bf(pv[i].x) | ((uint_t)f2bf(pv[i].y)<<16);
    }
  }
  // stage x rows (bf16, normalized) + diag
  {
    const int row = t>>1, half = t&1;
    const float2* xr = (const float2*)(x + ((size_t)blockIdx.x*128 + row)*DD + half*32);
    float ss = 0.f;
    #pragma unroll
    for (int i=0;i<16;++i){
      float2 a = xr[i];
      ss += a.x*a.x + a.y*a.y;
      uint_t w = (uint_t)f2bf(a.x*NORMALIZER) | ((uint_t)f2bf(a.y*NORMALIZER)<<16);
      *(uint_t*)(qs + row*72 + half*32 + i*2) = w;
    }
    ss += __shfl_xor(ss, 1);
    if (half==0) diags[row] = ss*DIAGF;
  }
  __syncthreads();

  const int l = t&63, wv = t>>6;
  const int wr0 = wv*32;
  float dv[2][4];
  #pragma unroll
  for (int rt=0;rt<2;++rt)
    #pragma unroll
    for (int r=0;r<4;++r) dv[rt][r] = diags[wr0 + rt*16 + ((l>>4)<<2) + r];

  float rmax[2][4];
  #pragma unroll
  for (int rt=0;rt<2;++rt){ rmax[rt][0]=-3e38f; rmax[rt][1]=-3e38f; rmax[rt][2]=-3e38f; rmax[rt][3]=-3e38f; }

  const size_t growb = (size_t)blockIdx.x*128;
  for (int mt=0; mt<17; ++mt){
    bf16x8 b0 = frag_ld(pjs, 72, mt*16, 0);
    bf16x8 b1 = frag_ld(pjs, 72, mt*16, 32);
    const int m = mt*16 + (l&15);
    const bool valid = (m < MM);
    #pragma unroll
    for (int rt=0;rt<2;++rt){
      bf16x8 a0 = frag_ld(qs, 72, wr0+rt*16, 0);
      bf16x8 a1 = frag_ld(qs, 72, wr0+rt*16, 32);
      f32x4 acc = {0.f,0.f,0.f,0.f};
      acc = mfma16(a0, b0, acc);
      acc = mfma16(a1, b1, acc);
      #pragma unroll
      for (int r=0;r<4;++r){
        float sp = acc[r] - dv[rt][r] + SBIAS;
        if (valid){
          rmax[rt][r] = fmaxf(rmax[rt][r], sp);
          sbuf[(growb + wr0 + rt*16 + ((l>>4)<<2) + r)*MM + m] = f2bf(sp);
        }
      }
    }
  }
  #pragma unroll
  for (int rt=0;rt<2;++rt){
    #pragma unroll
    for (int r=0;r<4;++r){
      float m = rmax[rt][r];
      m = fmaxf(m, __shfl_xor(m,1)); m = fmaxf(m, __shfl_xor(m,2));
      m = fmaxf(m, __shfl_xor(m,4)); m = fmaxf(m, __shfl_xor(m,8));
      if ((l&15)==0)
        rowsub[growb + wr0 + rt*16 + ((l>>4)<<2) + r] = m + dv[rt][r];
    }
  }
}

// ---------------- global max (2-stage) ----------------

__global__ __launch_bounds__(256) void k_gmax1(const float* __restrict__ rowsub,
                                               float* __restrict__ part){
  __shared__ float s[4];
  int t = threadIdx.x;
  float m = rowsub[(size_t)blockIdx.x*256 + t];
  #pragma unroll
  for (int off=32; off>0; off>>=1) m = fmaxf(m, __shfl_xor(m, off));
  if ((t&63)==0) s[t>>6] = m;
  __syncthreads();
  if (t==0) part[blockIdx.x] = fmaxf(fmaxf(s[0],s[1]), fmaxf(s[2],s[3]));
}

__global__ __launch_bounds__(256) void k_gmax2(const float* __restrict__ part,
                                               float* __restrict__ gmax){
  __shared__ float s[4];
  int t = threadIdx.x;
  float m = fmaxf(part[t], part[t+256]);
  #pragma unroll
  for (int off=32; off>0; off>>=1) m = fmaxf(m, __shfl_xor(m, off));
  if ((t&63)==0) s[t>>6] = m;
  __syncthreads();
  if (t==0) gmax[0] = fmaxf(fmaxf(s[0],s[1]), fmaxf(s[2],s[3]));
}

// ---------------- finalize: buf = ratio*(exp(s' - sub) + eps), in-place ----------------

__global__ __launch_bounds__(256) void k_fin(ushort_t* __restrict__ buf,
                                             const float* __restrict__ subarr,
                                             const float* __restrict__ gmaxp,
                                             int perrow){
  const int NU = NROWS*133;  // uints; 133 uints per row (266 shorts)
  uint_t* b32 = (uint_t*)buf;
  const float g = gmaxp[0];
  for (int i = blockIdx.x*256 + threadIdx.x; i < NU; i += gridDim.x*256){
    int row = (int)(((unsigned)i) / 133u);
    float sub = perrow ? subarr[row] : g;
    uint_t w = b32[i];
    float a, b; unpack2(w, a, b);
    a = RATIO*(__expf(a - sub) + KEPS);
    b = RATIO*(__expf(b - sub) + KEPS);
    b32[i] = (uint_t)f2bf(a) | ((uint_t)f2bf(b)<<16);
  }
}

// ---------------- chunk sums via MFMA: CTX_c = kp^T v, z_c = colsum(kp) ----------------

__global__ __launch_bounds__(256) void k_chunksum2(const ushort_t* __restrict__ kp,
                                                   const float* __restrict__ v,
                                                   float* __restrict__ ctx,
                                                   float* __restrict__ z){
  __shared__ __align__(16) ushort_t kpT[272*34];  // [m][row-subtile 32]
  __shared__ __align__(16) ushort_t vT[64*136];   // [e][row 128]
  const int blk = blockIdx.x, bh = blk>>5, ch = blk&31;
  const int t = threadIdx.x, l = t&63, wv = t>>6;
  const int row0 = ch*CCH;
  const ushort_t* kg = kp + (size_t)(bh*NSEQ + row0)*MM;
  const float*    vg = v  + (size_t)(bh*NSEQ + row0)*DD;

  // stage V transposed (batched loads)
  {
    const int e = t&63, r0i = t>>6;
    float rv[32];
    #pragma unroll
    for (int i=0;i<32;++i) rv[i] = vg[(size_t)(r0i + 4*i)*DD + e];
    #pragma unroll
    for (int i=0;i<32;++i) vT[e*136 + r0i + 4*i] = f2bf(rv[i]);
  }

  f32x4 acc[17];
  #pragma unroll
  for (int i=0;i<17;++i) acc[i] = (f32x4){0.f,0.f,0.f,0.f};
  float zacc = 0.f, zacc2 = 0.f;
  const bool hasz2 = (256 + t) < MM;

  for (int ks=0; ks<4; ++ks){
    __syncthreads();
    // stage kp^T rows ks*32..+31 (batched: 8 rows/wave, lanes walk m)
    {
      ushort_t rv[40];
      #pragma unroll
      for (int rr=0; rr<8; ++rr){
        const ushort_t* src = kg + (size_t)(ks*32 + wv*8 + rr)*MM;
        #pragma unroll
        for (int j=0;j<5;++j){
          int m = l + j*64;
          rv[rr*5+j] = (m < MM) ? src[m] : (ushort_t)0;
        }
      }
      #pragma unroll
      for (int rr=0; rr<8; ++rr){
        #pragma unroll
        for (int j=0;j<5;++j){
          int m = l + j*64;
          if (m < 272) kpT[m*34 + wv*8 + rr] = rv[rr*5+j];
        }
      }
    }
    __syncthreads();
    {
      float s1 = 0.f, s2 = 0.f;
      #pragma unroll
      for (int r=0;r<32;++r){
        s1 += bf2f(kpT[t*34 + r]);
        if (t < 16) s2 += bf2f(kpT[(256+t)*34 + r]);
      }
      zacc += s1; zacc2 += s2;
    }
    bf16x8 bv = frag_ld(vT, 136, wv*16, ks*32);
    #pragma unroll
    for (int mt=0; mt<17; ++mt){
      bf16x8 a = frag_ld(kpT, 34, mt*16, 0);
      acc[mt] = mfma16(a, bv, acc[mt]);
    }
  }

  float* cg = ctx + (size_t)blk*MM*DD;
  const int e = wv*16 + (l&15);
  #pragma unroll
  for (int mt=0; mt<17; ++mt){
    #pragma unroll
    for (int r=0;r<4;++r){
      int m = mt*16 + ((l>>4)<<2) + r;
      if (m < MM) cg[(size_t)m*DD + e] = acc[mt][r];
    }
  }
  float* zgo = z + (size_t)blk*MM;
  zgo[t] = zacc;
  if (hasz2) zgo[256+t] = zacc2;
}

// ---------------- exclusive prefix over chunks (batched) ----------------

__global__ __launch_bounds__(256) void k_prefix_ctx2(float* __restrict__ ctx){
  int blk = blockIdx.x; int bh = blk/67, mg = blk%67;
  int t = threadIdx.x; int mo = t>>6, e = t&63;
  int m = mg*4 + mo;
  if (m >= MM) return;
  size_t base = (size_t)bh*NCH*MM*DD + (size_t)m*DD + e;
  float vals[32];
  #pragma unroll
  for (int c=0;c<NCH;++c) vals[c] = ctx[base + (size_t)c*MM*DD];
  float run = 0.f;
  #pragma unroll
  for (int c=0;c<NCH;++c){
    float cur = vals[c];
    ctx[base + (size_t)c*MM*DD] = run;
    run += cur;
  }
}

__global__ __launch_bounds__(256) void k_prefix_z2(float* __restrict__ z){
  int bh = blockIdx.x, t = threadIdx.x;
  size_t base = (size_t)bh*NCH*MM;
  {
    float va[32];
    #pragma unroll
    for (int c=0;c<NCH;++c) va[c] = z[base + (size_t)c*MM + t];
    float run = 0.f;
    #pragma unroll
    for (int c=0;c<NCH;++c){ float cur = va[c]; z[base + (size_t)c*MM + t] = run; run += cur; }
  }
  if (256 + t < MM){
    float vb[32];
    #pragma unroll
    for (int c=0;c<NCH;++c) vb[c] = z[base + (size_t)c*MM + 256 + t];
    float run = 0.f;
    #pragma unroll
    for (int c=0;c<NCH;++c){ float cur = vb[c]; z[base + (size_t)c*MM + 256 + t] = run; run += cur; }
  }
}

// ---------------- per-chunk output (MFMA, register-prefetched staging) ----------------

__global__ __launch_bounds__(256) void k_output6(const ushort_t* __restrict__ qp,
                                                 const ushort_t* __restrict__ kp,
                                                 const float* __restrict__ v,
                                                 const float* __restrict__ ctx,
                                                 const float* __restrict__ z,
                                                 float* __restrict__ out){
  __shared__ __align__(16) char lds[65536];
  ushort_t* qs   = (ushort_t*)lds;            // [128][72]  18,432 B
  ushort_t* kps  = (ushort_t*)(lds + 18432);  // [128][72]  18,432 B
  ushort_t* Ps   = (ushort_t*)lds;            // [128][136] 34,816 B (aliases qs+kps)
  ushort_t* vT   = (ushort_t*)(lds + 36864);  // [64][136]  17,408 B
  ushort_t* ctxT = (ushort_t*)(lds + 54272);  // [64][74]    9,472 B
  float*    zs   = (float*)(lds + 63744);     // [320]       1,280 B
  float*    Drow = (float*)(lds + 65024);     // [128]         512 B

  const int blk = blockIdx.x, bh = blk>>5, ch = blk&31;
  const int t = threadIdx.x, l = t&63, wv = t>>6;
  const int row0 = ch*CCH;
  const int wr0 = wv*32;

  const ushort_t* qg = qp + (size_t)(bh*NSEQ + row0)*MM;
  const ushort_t* kg = kp + (size_t)(bh*NSEQ + row0)*MM;
  const float*    vg = v  + (size_t)(bh*NSEQ + row0)*DD;
  const float*  ctxg = ctx + (size_t)blk*MM*DD;
  const float*    zg = z  + (size_t)blk*MM;

  // prologue staging: V transposed (batched) + z prefix
  {
    const int e = t&63, r0i = t>>6;
    float rv[32];
    #pragma unroll
    for (int i=0;i<32;++i) rv[i] = vg[(size_t)(r0i + 4*i)*DD + e];
    #pragma unroll
    for (int i=0;i<32;++i) vT[e*136 + r0i + 4*i] = f2bf(rv[i]);
  }
  for (int i=t;i<320;i+=256) zs[i] = (i<MM) ? zg[i] : 0.f;

  // register prefetch state
  const int mcol  = (t&31)<<1;   // q/k: m-offset within 64-tile (uint granularity)
  const int qrow0 = t>>5;        // q/k: rows qrow0 + 8i
  const int ce    = t&63;        // ctx: e
  const int cm0   = t>>6;        // ctx: mm = cm0 + 4i
  uint_t rq[16], rk[16];
  float  rc[16];

#define LOADREGS(MT) do{ \
    const int m0_ = (MT)*64; \
    const bool vq_ = (m0_ + mcol) < MM; \
    _Pragma("unroll") \
    for (int i=0;i<16;++i){ \
      int row_ = qrow0 + 8*i; \
      rq[i] = vq_ ? *(const uint_t*)(qg + (size_t)row_*MM + m0_ + mcol) : 0u; \
      rk[i] = vq_ ? *(const uint_t*)(kg + (size_t)row_*MM + m0_ + mcol) : 0u; \
    } \
    _Pragma("unroll") \
    for (int i=0;i<16;++i){ \
      int mm_ = cm0 + 4*i; \
      rc[i] = (m0_ + mm_ < MM) ? ctxg[(size_t)(m0_ + mm_)*DD + ce] : 0.f; \
    } \
  }while(0)

#define WRITELDS() do{ \
    _Pragma("unroll") \
    for (int i=0;i<16;++i){ \
      int row_ = qrow0 + 8*i; \
      *(uint_t*)(qs  + row_*72 + mcol) = rq[i]; \
      *(uint_t*)(kps + row_*72 + mcol) = rk[i]; \
    } \
    _Pragma("unroll") \
    for (int i=0;i<16;++i) ctxT[ce*74 + cm0 + 4*i] = f2bf(rc[i]); \
  }while(0)

  f32x4 acc[2][8];
  f32x4 oacc[2][4];
  #pragma unroll
  for (int rt=0;rt<2;++rt){
    #pragma unroll
    for (int ct=0;ct<8;++ct) acc[rt][ct] = (f32x4){0.f,0.f,0.f,0.f};
    #pragma unroll
    for (int et=0;et<4;++et) oacc[rt][et] = (f32x4){0.f,0.f,0.f,0.f};
  }

  float Dz = 0.f;
  const int rD = t>>1, hD = t&1;

  LOADREGS(0);
  for (int mt=0; mt<5; ++mt){
    if (mt) __syncthreads();          // all readers of previous tile done
    WRITELDS();
    __syncthreads();
    if (mt < 4) LOADREGS(mt+1);       // async: overlaps MFMA below

    bf16x8 aq[2][2];
    #pragma unroll
    for (int rt=0;rt<2;++rt){
      aq[rt][0] = frag_ld(qs, 72, wr0+rt*16, 0);
      aq[rt][1] = frag_ld(qs, 72, wr0+rt*16, 32);
    }
    #pragma unroll
    for (int ct=0;ct<8;++ct){
      bf16x8 b0 = frag_ld(kps, 72, ct*16, 0);
      bf16x8 b1 = frag_ld(kps, 72, ct*16, 32);
      #pragma unroll
      for (int rt=0;rt<2;++rt){
        acc[rt][ct] = mfma16(aq[rt][0], b0, acc[rt][ct]);
        acc[rt][ct] = mfma16(aq[rt][1], b1, acc[rt][ct]);
      }
    }
    #pragma unroll
    for (int et=0;et<4;++et){
      bf16x8 b0 = frag_ld(ctxT, 74, et*16, 0);
      bf16x8 b1 = frag_ld(ctxT, 74, et*16, 32);
      #pragma unroll
      for (int rt=0;rt<2;++rt){
        oacc[rt][et] = mfma16(aq[rt][0], b0, oacc[rt][et]);
        oacc[rt][et] = mfma16(aq[rt][1], b1, oacc[rt][et]);
      }
    }
    {
      float s = 0.f;
      const int base = rD*72 + hD*32;
      #pragma unroll
      for (int mm=0;mm<32;++mm) s += bf2f(qs[base + mm]) * zs[mt*64 + hD*32 + mm];
      Dz += s;
    }
  }
  __syncthreads();  // all MFMA/Dz readers done before Ps overwrites qs/kps

  // ---- mask + row-sum + write P (bf16) to LDS ----
  float ds[2][4];
  #pragma unroll
  for (int rt=0;rt<2;++rt){ ds[rt][0]=0.f; ds[rt][1]=0.f; ds[rt][2]=0.f; ds[rt][3]=0.f; }
  #pragma unroll
  for (int rt=0;rt<2;++rt){
    #pragma unroll
    for (int ct=0;ct<8;++ct){
      #pragma unroll
      for (int r=0;r<4;++r){
        int i = wr0 + rt*16 + ((l>>4)<<2) + r;
        int j = ct*16 + (l&15);
        float m = (j <= i) ? acc[rt][ct][r] : 0.f;
        acc[rt][ct][r] = m;
        ds[rt][r] += m;
      }
    }
  }
  #pragma unroll
  for (int rt=0;rt<2;++rt){
    #pragma unroll
    for (int ct=0;ct<8;++ct){
      #pragma unroll
      for (int r=0;r<4;++r){
        int i = wr0 + rt*16 + ((l>>4)<<2) + r;
        Ps[i*136 + ct*16 + (l&15)] = f2bf(acc[rt][ct][r]);
      }
    }
  }
  #pragma unroll
  for (int rt=0;rt<2;++rt){
    #pragma unroll
    for (int r=0;r<4;++r){
      float d = ds[rt][r];
      d += __shfl_xor(d,1); d += __shfl_xor(d,2); d += __shfl_xor(d,4); d += __shfl_xor(d,8);
      if ((l&15)==0) Drow[wr0 + rt*16 + ((l>>4)<<2) + r] = d;
    }
  }
  __syncthreads();

  Dz += __shfl_xor(Dz, 1);
  if (hD==0) Drow[rD] += Dz;
  __syncthreads();

  // ---- PV: oacc += P V ----
  #pragma unroll
  for (int kt=0;kt<4;++kt){
    bf16x8 ap[2];
    #pragma unroll
    for (int rt=0;rt<2;++rt) ap[rt] = frag_ld(Ps, 136, wr0+rt*16, kt*32);
    #pragma unroll
    for (int et=0;et<4;++et){
      bf16x8 bv = frag_ld(vT, 136, et*16, kt*32);
      #pragma unroll
      for (int rt=0;rt<2;++rt) oacc[rt][et] = mfma16(ap[rt], bv, oacc[rt][et]);
    }
  }

  // ---- epilogue ----
  float* og = out + (size_t)(bh*NSEQ + row0)*DD;
  #pragma unroll
  for (int rt=0;rt<2;++rt){
    #pragma unroll
    for (int r=0;r<4;++r){
      int i = wr0 + rt*16 + ((l>>4)<<2) + r;
      float dinv = 1.0f / Drow[i];
      #pragma unroll
      for (int et=0;et<4;++et)
        og[(size_t)i*DD + et*16 + (l&15)] = oacc[rt][et][r] * dinv;
    }
  }
#undef LOADREGS
#undef WRITELDS
}

// ---------------- launch ----------------

extern "C" void kernel_launch(void* const* d_in, const int* in_sizes, int n_in,
                              void* d_out, int out_size, void* d_ws, size_t ws_size,
                              hipStream_t stream) {
  const float* q    = (const float*)d_in[0];
  const float* k    = (const float*)d_in[1];
  const float* v    = (const float*)d_in[2];
  const float* proj = (const float*)d_in[3];
  float* out = (float*)d_out;
  char* ws = (char*)d_ws;

  const size_t QP_OFF   = 0;             // bf16 [rows][266]
  const size_t KP_OFF   = 69730304ull;   // bf16 [rows][266]
  const size_t CTX_OFF  = 139460608ull;  // f32  [1024][266][64]
  const size_t Z_OFF    = 209190912ull;  // f32  [1024][266]
  const size_t RSUB_OFF = 210280448ull;  // f32  [rows]
  const size_t PART_OFF = 210804736ull;  // f32  [512]
  const size_t GMAX_OFF = 210806784ull;  // f32  [1]
  if (ws_size < 210807000ull) return;

  ushort_t* qp   = (ushort_t*)(ws + QP_OFF);
  ushort_t* kp   = (ushort_t*)(ws + KP_OFF);
  float* ctx     = (float*)(ws + CTX_OFF);
  float* z       = (float*)(ws + Z_OFF);
  float* rowsub  = (float*)(ws + RSUB_OFF);
  float* part    = (float*)(ws + PART_OFF);
  float* gmax    = (float*)(ws + GMAX_OFF);

  // q side: dash -> per-row finalize (stream order makes rowsub reuse safe)
  k_dash <<<NROWS/128, 256, 0, stream>>>(q, proj, qp, rowsub);
  k_fin  <<<2048, 256, 0, stream>>>(qp, rowsub, gmax, 1);
  // k side: dash -> global max -> finalize
  k_dash <<<NROWS/128, 256, 0, stream>>>(k, proj, kp, rowsub);
  k_gmax1<<<512, 256, 0, stream>>>(rowsub, part);
  k_gmax2<<<1, 256, 0, stream>>>(part, gmax);
  k_fin  <<<2048, 256, 0, stream>>>(kp, rowsub, gmax, 0);

  k_chunksum2 <<<NBH*NCH, 256, 0, stream>>>(kp, v, ctx, z);
  k_prefix_ctx2<<<NBH*67, 256, 0, stream>>>(ctx);
  k_prefix_z2 <<<NBH, 256, 0, stream>>>(z);
  k_output6   <<<NBH*NCH, 256, 0, stream>>>(qp, kp, v, ctx, z, out);
}